// Round 3
// baseline (2422.992 us; speedup 1.0000x reference)
//
#include <hip/hip_runtime.h>
#include <cstdint>

typedef _Float16 half8 __attribute__((ext_vector_type(8)));
typedef _Float16 h2f __attribute__((ext_vector_type(2)));
typedef float f32x4 __attribute__((ext_vector_type(4)));

__device__ __forceinline__ float leakyf(float v){ return v > 0.f ? v : 0.01f*v; }
__device__ __forceinline__ float actf(float v, int act){
  if (act == 1) return fmaxf(v, 0.f);
  if (act == 2) return leakyf(v);
  return v;
}

__device__ __forceinline__ void gl_lds16(const void* g, void* l){
  __builtin_amdgcn_global_load_lds((const __attribute__((address_space(1))) void*)g,
                                   (__attribute__((address_space(3))) void*)l, 16, 0, 0);
}

// ---------------- graph build ----------------
__global__ void k_init_deg(int* deg_out, int* deg_in, int n){
  int i = blockIdx.x*blockDim.x + threadIdx.x;
  if (i < n){ deg_out[i] = 1; deg_in[i] = 1; }
}
__global__ void k_count(const int* __restrict__ src, const int* __restrict__ dst,
                        int* deg_out, int* deg_in, int e){
  int i = blockIdx.x*blockDim.x + threadIdx.x;
  if (i < e){ atomicAdd(&deg_out[src[i]], 1); atomicAdd(&deg_in[dst[i]], 1); }
}
__global__ void k_scan(const int* __restrict__ deg, int* rp, int n){
  __shared__ int sums[1024];
  int t = threadIdx.x;
  int per = (n + 1023)/1024;
  int base = t*per;
  int s = 0;
  for (int i = 0; i < per; ++i){ int j = base+i; if (j < n) s += deg[j]; }
  sums[t] = s; __syncthreads();
  for (int off = 1; off < 1024; off <<= 1){
    int v = 0;
    if (t >= off) v = sums[t-off];
    __syncthreads();
    if (t >= off) sums[t] += v;
    __syncthreads();
  }
  int run = (t == 0) ? 0 : sums[t-1];
  for (int i = 0; i < per; ++i){ int j = base+i; if (j < n){ rp[j] = run; run += deg[j]; } }
  if (t == 1023) rp[n] = sums[1023];
}
__global__ void k_zero_i(int* p, int n){ int i=blockIdx.x*blockDim.x+threadIdx.x; if(i<n) p[i]=0; }
__global__ void k_zero_f(float* p, int n){ int i=blockIdx.x*blockDim.x+threadIdx.x; if(i<n) p[i]=0.f; }
__global__ void k_fill(const int* __restrict__ src, const int* __restrict__ dst,
                       const int* __restrict__ rp, int* cursor, int* ci, int e, int n){
  int i = blockIdx.x*blockDim.x + threadIdx.x;
  if (i >= e + n) return;
  int s, d;
  if (i < e){ s = src[i]; d = dst[i]; } else { s = d = i - e; }
  int pos = atomicAdd(&cursor[d], 1);
  ci[rp[d] + pos] = s;
}
__global__ void k_norms(const int* deg_out, const int* deg_in, float* nsrc, float* ndst, int n){
  int i = blockIdx.x*blockDim.x + threadIdx.x;
  if (i < n){ nsrc[i] = rsqrtf((float)deg_out[i]); ndst[i] = rsqrtf((float)deg_in[i]); }
}

// ---------------- conversions ----------------
__global__ void k_conv_a(const float* __restrict__ in, _Float16* __restrict__ out,
                         int M, int K, int Mp, int Kp){
  long idx = (long)blockIdx.x*blockDim.x + threadIdx.x;
  long total = (long)Mp*(Kp/8);
  if (idx >= total) return;
  int kp8 = Kp/8;
  int m = (int)(idx / kp8);
  int k8 = (int)(idx % kp8) * 8;
  half8 o;
  #pragma unroll
  for (int j=0;j<8;++j){
    int k = k8+j;
    o[j] = (_Float16)((m<M && k<K) ? in[(size_t)m*K + k] : 0.f);
  }
  *(half8*)&out[(size_t)m*Kp + k8] = o;
}
__global__ void k_conv_bt(const float* __restrict__ in, _Float16* __restrict__ out,
                          int K, int N, int Np, int Kp){
  __shared__ float t[32][33];
  int kb = blockIdx.x*32, nb = blockIdx.y*32;
  int tx = threadIdx.x & 31, ty = threadIdx.x >> 5;
  for (int r=ty; r<32; r+=8){
    int k = kb+r, n = nb+tx;
    t[r][tx] = (k<K && n<N) ? in[(size_t)k*N+n] : 0.f;
  }
  __syncthreads();
  for (int r=ty; r<32; r+=8){
    int n = nb+r, k = kb+tx;
    if (n<Np && k<Kp) out[(size_t)n*Kp+k] = (_Float16)t[tx][r];
  }
}

// ---------------- fp16 MFMA GEMM: C = act(A @ B^T + bias) ----------------
template<int ACT, bool BIAS, bool F32OUT, bool F16OUT>
__global__ __launch_bounds__(256) void k_hgemm(
    const _Float16* __restrict__ A, const _Float16* __restrict__ BT,
    const float* __restrict__ bias, float* __restrict__ C, _Float16* __restrict__ Ch,
    int M, int Nvalid, long Np, long Kp)
{
  __shared__ __align__(16) _Float16 Asm[128*32];
  __shared__ __align__(16) _Float16 Bsm[128*32];
  const int m0 = blockIdx.y*128, n0 = blockIdx.x*128;
  const int tid = threadIdx.x;
  const int l = tid & 63, w = tid >> 6;
  const int wr = w >> 1, wc = w & 1;
  const int srow = tid >> 2, sseg = tid & 3;
  f32x4 acc[4][4] = {};

  for (long k0 = 0; k0 < Kp; k0 += 32){
    #pragma unroll
    for (int i=0;i<2;++i){
      int ar = i*64 + srow;
      gl_lds16(A  + (size_t)(m0+ar)*Kp + k0 + sseg*8, (char*)Asm + i*4096 + (size_t)tid*16);
      gl_lds16(BT + (size_t)(n0+ar)*Kp + k0 + sseg*8, (char*)Bsm + i*4096 + (size_t)tid*16);
    }
    __syncthreads();
    half8 af[4], bf[4];
    #pragma unroll
    for (int mi=0;mi<4;++mi)
      af[mi] = *(const half8*)&Asm[(size_t)(wr*64 + mi*16 + (l&15))*32 + (l>>4)*8];
    #pragma unroll
    for (int nj=0;nj<4;++nj)
      bf[nj] = *(const half8*)&Bsm[(size_t)(wc*64 + nj*16 + (l&15))*32 + (l>>4)*8];
    #pragma unroll
    for (int mi=0;mi<4;++mi)
      #pragma unroll
      for (int nj=0;nj<4;++nj)
        acc[mi][nj] = __builtin_amdgcn_mfma_f32_16x16x32_f16(af[mi], bf[nj], acc[mi][nj], 0,0,0);
    __syncthreads();
  }

  const int cr = (l>>4)*4, cc = l&15;
  #pragma unroll
  for (int mi=0;mi<4;++mi){
    #pragma unroll
    for (int nj=0;nj<4;++nj){
      int cbase = n0 + wc*64 + nj*16 + cc;
      bool cvalid = cbase < Nvalid;
      #pragma unroll
      for (int q=0;q<4;++q){
        int r = m0 + wr*64 + mi*16 + cr + q;
        float v = acc[mi][nj][q];
        if (BIAS && cvalid) v += bias[cbase];
        if (ACT==1) v = fmaxf(v,0.f); else if (ACT==2) v = leakyf(v);
        if (!cvalid) v = 0.f;
        if (F32OUT){ if (r < M && cvalid) C[(size_t)r*Nvalid + cbase] = v; }
        if (F16OUT){ Ch[(size_t)r*Np + cbase] = (_Float16)(r < M ? v : 0.f); }
      }
    }
  }
}

// ---------------- skinny 10-out GEMM with LDS-staged transposed f32 weights ----------------
// out[r][c] = act(sum_k A[r][k]*W[k][c] + bias[c]), W staged as wl[c][k]
template<typename T>
__global__ __launch_bounds__(256) void k_skinny10_lds(
    const T* __restrict__ A, long lda, const float* __restrict__ W, int K,
    const float* __restrict__ bias, float* __restrict__ out, int M, int act)
{
  __shared__ float wl[10*2048];   // 80 KB
  int tid = threadIdx.x;
  for (int idx = tid; idx < K*10; idx += 256){
    int k = idx/10, c = idx - k*10;
    wl[c*K + k] = W[idx];
  }
  __syncthreads();
  int wv = tid >> 6, lane = tid & 63;
  int stride = gridDim.x*4;
  for (int row = blockIdx.x*4 + wv; row < M; row += stride){
    const T* a = A + (size_t)row*lda;
    float acc[10];
    #pragma unroll
    for (int c=0;c<10;++c) acc[c]=0.f;
    for (int k = lane; k < K; k += 64){
      float av = (float)a[k];
      #pragma unroll
      for (int c=0;c<10;++c) acc[c] += av*wl[c*K + k];
    }
    #pragma unroll
    for (int c=0;c<10;++c){
      #pragma unroll
      for (int off=32; off; off>>=1) acc[c] += __shfl_down(acc[c], off);
    }
    if (lane == 0){
      #pragma unroll
      for (int c=0;c<10;++c){
        float v = acc[c] + (bias ? bias[c] : 0.f);
        out[(size_t)row*10 + c] = actf(v, act);
      }
    }
  }
}

// ---------------- decoder layer 1: weights in registers, rows looped ----------------
__global__ __launch_bounds__(512) void k_broad_reg(
    const float* __restrict__ Z, const float* __restrict__ W, const float* __restrict__ bias,
    _Float16* __restrict__ out, int M, int Mp, int Cc /*2000*/, int Cp /*2048*/)
{
  int tid = threadIdx.x;
  float wr[4][10], bv[4];
  #pragma unroll
  for (int j=0;j<4;++j){
    int c = tid + j*512;
    bool v = c < Cc;
    bv[j] = v ? bias[c] : 0.f;
    #pragma unroll
    for (int q=0;q<10;++q) wr[j][q] = v ? W[(size_t)q*Cc + c] : 0.f;
  }
  for (int row = blockIdx.x; row < Mp; row += gridDim.x){
    float zr[10];
    bool rv = row < M;
    #pragma unroll
    for (int q=0;q<10;++q) zr[q] = rv ? Z[(size_t)row*10 + q] : 0.f;
    #pragma unroll
    for (int j=0;j<4;++j){
      int c = tid + j*512;
      float v = bv[j];
      #pragma unroll
      for (int q=0;q<10;++q) v += zr[q]*wr[j][q];
      v = fmaxf(v, 0.f);
      out[(size_t)row*Cp + c] = (_Float16)((rv && c < Cc) ? v : 0.f);
    }
  }
}

// ---------------- fused gate (leaky->softmax->l2) + mix -> fp16 padded out ----------------
__global__ void k_gate_mix_h(const float* __restrict__ tra, const float* __restrict__ zin,
                             const float* __restrict__ w, const float* __restrict__ b,
                             _Float16* __restrict__ mix, int W, int Wp)
{
  int row = blockIdx.x;
  int tid = threadIdx.x;
  const float* tr = tra + (size_t)row*W;
  const float* zr = zin + (size_t)row*W;
  float a0=0.f, a1=0.f;
  for (int k=tid; k<W; k+=256){ float t = tr[k]; a0 += t*w[2*k];       a1 += t*w[2*k+1]; }
  for (int k=tid; k<W; k+=256){ float zv = zr[k]; a0 += zv*w[2*(W+k)]; a1 += zv*w[2*(W+k)+1]; }
  #pragma unroll
  for (int off=32; off; off>>=1){ a0 += __shfl_down(a0,off); a1 += __shfl_down(a1,off); }
  __shared__ float red0[4], red1[4], m01[2];
  int wv = tid>>6, ln = tid&63;
  if (ln==0){ red0[wv]=a0; red1[wv]=a1; }
  __syncthreads();
  if (tid==0){
    float s0 = red0[0]+red0[1]+red0[2]+red0[3] + b[0];
    float s1 = red1[0]+red1[1]+red1[2]+red1[3] + b[1];
    s0 = leakyf(s0); s1 = leakyf(s1);
    float mx = fmaxf(s0,s1);
    float e0 = expf(s0-mx), e1 = expf(s1-mx);
    float inv = rsqrtf(fmaxf(e0*e0+e1*e1, 1e-30f));
    m01[0] = e0*inv; m01[1] = e1*inv;
  }
  __syncthreads();
  float mz = m01[0], mt = m01[1];
  for (int k=tid; k<W; k+=256){
    float t = tr[k], zv = zr[k];
    mix[(size_t)row*Wp + k] = (_Float16)(mz*zv + mt*t);
  }
}

// ---------------- SpMM gather: fp16 in (stride Wp), f32 or fp16 out ----------------
template<int ACT, bool F16OUT>
__global__ void k_spmm_h(const _Float16* __restrict__ h, const int* __restrict__ rp,
                         const int* __restrict__ ci, const float* __restrict__ nsrc,
                         const float* __restrict__ ndst, float* __restrict__ outf,
                         _Float16* __restrict__ outh, int W, int Wp)
{
  int row = blockIdx.x;
  int tid = threadIdx.x;
  int e0 = rp[row], e1 = rp[row+1];
  int c0 = tid, c1 = tid+128, c2 = tid+256, c3 = tid+384;
  float acc0=0.f, acc1=0.f, acc2=0.f, acc3=0.f;
  for (int e=e0; e<e1; ++e){
    int s = ci[e];
    float ns = nsrc[s];
    const _Float16* hr = h + (size_t)s*Wp;
    acc0 += ns*(float)hr[c0];
    if (c1 < W) acc1 += ns*(float)hr[c1];
    if (c2 < W) acc2 += ns*(float)hr[c2];
    if (c3 < W) acc3 += ns*(float)hr[c3];
  }
  float nd = ndst[row];
  if (F16OUT){
    outh[(size_t)row*Wp + c0] = (_Float16)(acc0*nd);
    outh[(size_t)row*Wp + c1] = (_Float16)(c1 < W ? acc1*nd : 0.f);
    outh[(size_t)row*Wp + c2] = (_Float16)(c2 < W ? acc2*nd : 0.f);
    outh[(size_t)row*Wp + c3] = (_Float16)(c3 < W ? acc3*nd : 0.f);
  } else {
    outf[(size_t)row*W + c0] = actf(acc0*nd, ACT);
    if (c1 < W) outf[(size_t)row*W + c1] = actf(acc1*nd, ACT);
    if (c2 < W) outf[(size_t)row*W + c2] = actf(acc2*nd, ACT);
    if (c3 < W) outf[(size_t)row*W + c3] = actf(acc3*nd, ACT);
  }
}

// ---------------- SpMM gather, width 10 ----------------
template<int ACT>
__global__ void k_spmm10(const float* __restrict__ h, const int* __restrict__ rp,
                         const int* __restrict__ ci, const float* __restrict__ nsrc,
                         const float* __restrict__ ndst, float* __restrict__ out, int n)
{
  int idx = blockIdx.x*blockDim.x + threadIdx.x;
  if (idx >= n*10) return;
  int row = idx/10, c = idx - row*10;
  int e0 = rp[row], e1 = rp[row+1];
  float acc = 0.f;
  for (int e=e0; e<e1; ++e){
    int s = ci[e];
    acc += nsrc[s]*h[(size_t)s*10 + c];
  }
  out[idx] = actf(acc*ndst[row], ACT);
}

// ---------------- fused u-gate + pre5: LDS-staged mlw(f32) + g5(fp16 pairs) ----------------
__device__ __forceinline__ float up5_load(const float* z1, const float* z2, const float* z3,
                                          const float* z4, const float* zz, int row, int k){
  if (k < 500)  return z1[(size_t)row*500  + k];
  if (k < 1000) return z2[(size_t)row*500  + k - 500];
  if (k < 3000) return z3[(size_t)row*2000 + k - 1000];
  if (k < 3010) return z4[(size_t)row*10   + k - 3000];
  return zz[(size_t)row*10 + k - 3010];
}

__global__ __launch_bounds__(512) void k_up5(
    const float* __restrict__ z1, const float* __restrict__ z2, const float* __restrict__ z3,
    const float* __restrict__ z4, const float* __restrict__ zz,
    const float* __restrict__ mlw, const float* __restrict__ mlb,
    const float* __restrict__ g5, float* __restrict__ pre5, int M)
{
  const int D = 3020;
  __shared__ float mlwl[5*3020];        // 60.4 KB
  __shared__ unsigned g5l[5*3020];      // 60.4 KB (fp16x2 per slot)
  int tid = threadIdx.x;
  for (int idx = tid; idx < D*5; idx += 512){
    int k = idx/5, c = idx - k*5;
    mlwl[c*D + k] = mlw[(size_t)k*5 + c];
  }
  for (int idx = tid; idx < D*5; idx += 512){
    int k = idx/5, jp = idx - k*5;
    h2f p;
    p[0] = (_Float16)g5[(size_t)k*10 + 2*jp];
    p[1] = (_Float16)g5[(size_t)k*10 + 2*jp + 1];
    g5l[jp*D + k] = __builtin_bit_cast(unsigned, p);
  }
  __syncthreads();
  int wv = tid >> 6, lane = tid & 63;
  int stride = gridDim.x*8;
  for (int row = blockIdx.x*8 + wv; row < M; row += stride){
    // pass A: u logits
    float a0=0.f,a1=0.f,a2=0.f,a3=0.f,a4=0.f;
    for (int k = lane; k < D; k += 64){
      float a = up5_load(z1,z2,z3,z4,zz,row,k);
      a0 += a*mlwl[0*D+k]; a1 += a*mlwl[1*D+k]; a2 += a*mlwl[2*D+k];
      a3 += a*mlwl[3*D+k]; a4 += a*mlwl[4*D+k];
    }
    #pragma unroll
    for (int m=1;m<64;m<<=1){
      a0 += __shfl_xor(a0,m); a1 += __shfl_xor(a1,m); a2 += __shfl_xor(a2,m);
      a3 += __shfl_xor(a3,m); a4 += __shfl_xor(a4,m);
    }
    float l0 = leakyf(a0+mlb[0]), l1 = leakyf(a1+mlb[1]), l2v = leakyf(a2+mlb[2]);
    float l3 = leakyf(a3+mlb[3]), l4 = leakyf(a4+mlb[4]);
    float mx = fmaxf(fmaxf(fmaxf(l0,l1),fmaxf(l2v,l3)),l4);
    float e0=expf(l0-mx), e1=expf(l1-mx), e2=expf(l2v-mx), e3=expf(l3-mx), e4=expf(l4-mx);
    float inv = rsqrtf(fmaxf(e0*e0+e1*e1+e2*e2+e3*e3+e4*e4, 1e-30f));
    float u0=e0*inv, u1=e1*inv, u2=e2*inv, u3=e3*inv, u4=e4*inv;
    // pass B: pre5 = (u-scaled row) @ g5
    float acc[10];
    #pragma unroll
    for (int c=0;c<10;++c) acc[c]=0.f;
    for (int k = lane; k < D; k += 64){
      float a = up5_load(z1,z2,z3,z4,zz,row,k);
      float s = (k<500) ? u0 : (k<1000) ? u1 : (k<3000) ? u2 : (k<3010) ? u3 : u4;
      a *= s;
      #pragma unroll
      for (int jp=0;jp<5;++jp){
        h2f p = __builtin_bit_cast(h2f, g5l[jp*D+k]);
        acc[2*jp]   += a*(float)p[0];
        acc[2*jp+1] += a*(float)p[1];
      }
    }
    #pragma unroll
    for (int c=0;c<10;++c){
      #pragma unroll
      for (int off=32; off; off>>=1) acc[c] += __shfl_down(acc[c], off);
    }
    if (lane == 0){
      #pragma unroll
      for (int c=0;c<10;++c) pre5[(size_t)row*10 + c] = acc[c];
    }
  }
}

__global__ void k_softmax10(const float* __restrict__ h, float* __restrict__ out, int M){
  int row = blockIdx.x*blockDim.x + threadIdx.x;
  if (row >= M) return;
  float v[10]; float mx=-1e30f;
  #pragma unroll
  for (int j=0;j<10;++j){ v[j]=h[(size_t)row*10+j]; mx=fmaxf(mx,v[j]); }
  float s=0.f;
  #pragma unroll
  for (int j=0;j<10;++j){ v[j]=expf(v[j]-mx); s+=v[j]; }
  float inv=1.f/s;
  #pragma unroll
  for (int j=0;j<10;++j) out[(size_t)row*10+j]=v[j]*inv;
}

__global__ void k_q(const float* __restrict__ z, const float* __restrict__ cluster,
                    float* __restrict__ qout, float* __restrict__ colsum, int M)
{
  __shared__ float part[10];
  if (threadIdx.x < 10) part[threadIdx.x] = 0.f;
  __syncthreads();
  int row = blockIdx.x*blockDim.x + threadIdx.x;
  if (row < M){
    float zr[10];
    #pragma unroll
    for (int j=0;j<10;++j) zr[j] = z[(size_t)row*10+j];
    float qv[10]; float s=0.f;
    #pragma unroll
    for (int k=0;k<10;++k){
      float d2=0.f;
      #pragma unroll
      for (int j=0;j<10;++j){ float t = zr[j]-cluster[k*10+j]; d2 += t*t; }
      float qq = 1.f/(1.f+d2);
      qv[k]=qq; s+=qq;
    }
    float inv = 1.f/s;
    #pragma unroll
    for (int k=0;k<10;++k){
      float val = qv[k]*inv;
      qout[(size_t)row*10+k] = val;
      atomicAdd(&part[k], val);
    }
  }
  __syncthreads();
  if (threadIdx.x < 10) atomicAdd(&colsum[threadIdx.x], part[threadIdx.x]);
}

__global__ void k_p(const float* __restrict__ q, const float* __restrict__ colsum,
                    float* __restrict__ pout, int M){
  int row = blockIdx.x*blockDim.x + threadIdx.x;
  if (row >= M) return;
  float w[10]; float s=0.f;
  #pragma unroll
  for (int k=0;k<10;++k){ float qq=q[(size_t)row*10+k]; float ww=qq*qq/colsum[k]; w[k]=ww; s+=ww; }
  float inv=1.f/s;
  #pragma unroll
  for (int k=0;k<10;++k) pout[(size_t)row*10+k]=w[k]*inv;
}

extern "C" void kernel_launch(void* const* d_in, const int* in_sizes, int n_in,
                              void* d_out, int out_size, void* d_ws, size_t ws_size,
                              hipStream_t stream)
{
  const float* x   = (const float*)d_in[0];
  const float* ew1 = (const float*)d_in[1];  const float* eb1 = (const float*)d_in[2];
  const float* ew2 = (const float*)d_in[3];  const float* eb2 = (const float*)d_in[4];
  const float* ew3 = (const float*)d_in[5];  const float* eb3 = (const float*)d_in[6];
  const float* zw  = (const float*)d_in[7];  const float* zb  = (const float*)d_in[8];
  const float* dw1 = (const float*)d_in[9];  const float* db1 = (const float*)d_in[10];
  const float* dw2 = (const float*)d_in[11]; const float* db2 = (const float*)d_in[12];
  const float* dw3 = (const float*)d_in[13]; const float* db3 = (const float*)d_in[14];
  const float* xw  = (const float*)d_in[15]; const float* xb  = (const float*)d_in[16];
  const float* g1  = (const float*)d_in[17];
  const float* g2  = (const float*)d_in[18];
  const float* g3  = (const float*)d_in[19];
  const float* g4  = (const float*)d_in[20];
  const float* g5  = (const float*)d_in[21];
  const float* m1w = (const float*)d_in[22]; const float* m1b = (const float*)d_in[23];
  const float* m2w = (const float*)d_in[24]; const float* m2b = (const float*)d_in[25];
  const float* m3w = (const float*)d_in[26]; const float* m3b = (const float*)d_in[27];
  const float* mlw = (const float*)d_in[28]; const float* mlb = (const float*)d_in[29];
  const float* cluster = (const float*)d_in[30];
  const int* src = (const int*)d_in[31];
  const int* dst = (const int*)d_in[32];

  const int NI=2000, H1=500, H2=500, H3=2000;
  const int N = in_sizes[0] / NI;      // 20000
  const int E = in_sizes[31];          // 320000
  const int M_tot = E + N;
  const int Mp = ((N + 127)/128)*128;  // 20096

  float* out = (float*)d_out;
  float* out_xbar = out;                          // N*NI
  float* out_q    = out + (size_t)N*NI;
  float* out_pred = out_q + (size_t)N*10;
  float* out_p    = out_pred + (size_t)N*10;

  // ---- workspace carve ----
  char* base = (char*)d_ws;
  size_t off = 0;
  auto AF = [&](size_t e)->float*{ float* r=(float*)(base+off); off += ((e*sizeof(float)+15)&~(size_t)15); return r; };
  auto AI = [&](size_t e)->int*  { int*   r=(int*)  (base+off); off += ((e*sizeof(int)  +15)&~(size_t)15); return r; };
  auto AH = [&](size_t e)->_Float16*{ _Float16* r=(_Float16*)(base+off); off += ((e*sizeof(_Float16)+15)&~(size_t)15); return r; };

  int* deg_out = AI(N); int* deg_in = AI(N);
  int* rp = AI(N+1); int* cursor = AI(N); int* ci = AI(M_tot);
  float* nsrc = AF(N); float* ndst = AF(N); float* colsum = AF(16);
  float* tra1 = AF((size_t)N*H1);
  float* tra2 = AF((size_t)N*H2);
  float* tra3 = AF((size_t)N*H3);
  float* zlat = AF((size_t)N*10);
  float* z1   = AF((size_t)N*H1);
  float* z2   = AF((size_t)N*H2);
  float* z3   = out_xbar;           // N*2000 f32 in x_bar slot (consumed before final GEMM)
  float* pre4 = AF((size_t)N*10);
  float* z4   = AF((size_t)N*10);
  float* pre5 = AF((size_t)N*10);
  float* hbuf = AF((size_t)N*10);
  // fp16 buffers
  _Float16* xh  = AH((size_t)Mp*2048);   // x_h -> mix3_h -> dh1_h
  _Float16* Ah1 = AH((size_t)Mp*512);    // tra1_h -> pre1_h -> agg2_h -> agg3_h -> dh3_h
  _Float16* Ah2 = AH((size_t)Mp*512);    // tra2_h -> mix1_h -> mix2_h -> dh2_h
  _Float16* ew1h = AH((size_t)512*2048);
  _Float16* ew2h = AH((size_t)512*512);
  _Float16* ew3h = AH((size_t)2048*512);
  _Float16* dw2h = AH((size_t)512*2048);
  _Float16* dw3h = AH((size_t)512*512);
  _Float16* xwh  = AH((size_t)2048*512);
  _Float16* g1h  = AH((size_t)512*2048);
  _Float16* g2h  = AH((size_t)512*512);
  _Float16* g3h  = AH((size_t)2048*512);
  (void)ws_size; (void)out_size; (void)n_in;

  dim3 b256(256);
  // ---- graph build ----
  k_init_deg<<<(N+255)/256, b256, 0, stream>>>(deg_out, deg_in, N);
  k_count<<<(E+255)/256, b256, 0, stream>>>(src, dst, deg_out, deg_in, E);
  k_scan<<<1, 1024, 0, stream>>>(deg_in, rp, N);
  k_zero_i<<<(N+255)/256, b256, 0, stream>>>(cursor, N);
  k_zero_f<<<1, 64, 0, stream>>>(colsum, 16);
  k_fill<<<(M_tot+255)/256, b256, 0, stream>>>(src, dst, rp, cursor, ci, E, N);
  k_norms<<<(N+255)/256, b256, 0, stream>>>(deg_out, deg_in, nsrc, ndst, N);

  // ---- conversions ----
  {
    long tot = (long)Mp*(2048/8);
    k_conv_a<<<(tot+255)/256, b256, 0, stream>>>(x, xh, N, NI, Mp, 2048);
  }
  #define CONVBT(W_, K_, N_, NP_, KP_, OUT_) \
    k_conv_bt<<<dim3((KP_)/32,(NP_)/32), b256, 0, stream>>>((W_), (OUT_), (K_), (N_), (NP_), (KP_))
  CONVBT(ew1, 2000, 500, 512, 2048, ew1h);
  CONVBT(ew2, 500, 500, 512, 512, ew2h);
  CONVBT(ew3, 500, 2000, 2048, 512, ew3h);
  CONVBT(dw2, 2000, 500, 512, 2048, dw2h);
  CONVBT(dw3, 500, 500, 512, 512, dw3h);
  CONVBT(xw,  500, 2000, 2048, 512, xwh);
  CONVBT(g1,  2000, 500, 512, 2048, g1h);
  CONVBT(g2,  500, 500, 512, 512, g2h);
  CONVBT(g3,  500, 2000, 2048, 512, g3h);
  #undef CONVBT

  const int MT = Mp/128;   // 157
  #define HGEMM(ACT,BIAS,F32O,F16O, A_,BT_,BIASP_,C_,CH_, NV_,NP_,KP_) \
    k_hgemm<ACT,BIAS,F32O,F16O><<<dim3((NP_)/128, MT), b256, 0, stream>>>( \
      (A_),(BT_),(BIASP_),(C_),(CH_), N, (NV_), (NP_), (KP_))

  // ---- encoder ----
  HGEMM(1,true, true, true,  xh,  ew1h, eb1, tra1, Ah1, 500, 512, 2048);   // tra1 + tra1_h
  HGEMM(1,true, true, true,  Ah1, ew2h, eb2, tra2, Ah2, 500, 512, 512);    // tra2 + tra2_h
  HGEMM(1,true, true, false, Ah2, ew3h, eb3, tra3, (_Float16*)nullptr, 2000, 2048, 512); // tra3
  k_skinny10_lds<float><<<512, b256, 0, stream>>>(tra3, 2000, zw, 2000, zb, zlat, N, 0);

  // ---- GCN branch ----
  HGEMM(0,false,false,true,  xh,  g1h, nullptr, (float*)nullptr, Ah1, 500, 512, 2048);   // pre1_h
  k_spmm_h<2,false><<<N, 128, 0, stream>>>(Ah1, rp, ci, nsrc, ndst, z1, (_Float16*)nullptr, H1, 512); // z1
  k_gate_mix_h<<<N, b256, 0, stream>>>(tra1, z1, m1w, m1b, Ah2, H1, 512);                // mix1_h
  k_spmm_h<0,true><<<N, 128, 0, stream>>>(Ah2, rp, ci, nsrc, ndst, (float*)nullptr, Ah1, H1, 512);    // agg2_h
  HGEMM(2,false,true, false, Ah1, g2h, nullptr, z2, (_Float16*)nullptr, 500, 512, 512);  // z2
  k_gate_mix_h<<<N, b256, 0, stream>>>(tra2, z2, m2w, m2b, Ah2, H2, 512);                // mix2_h
  k_spmm_h<0,true><<<N, 128, 0, stream>>>(Ah2, rp, ci, nsrc, ndst, (float*)nullptr, Ah1, H2, 512);    // agg3_h
  HGEMM(2,false,true, false, Ah1, g3h, nullptr, z3, (_Float16*)nullptr, 2000, 2048, 512); // z3
  k_gate_mix_h<<<N, b256, 0, stream>>>(tra3, z3, m3w, m3b, xh, H3, 2048);                // mix3_h
  k_skinny10_lds<_Float16><<<512, b256, 0, stream>>>(xh, 2048, g4, 2000, nullptr, pre4, N, 0);
  k_spmm10<2><<<(N*10+255)/256, b256, 0, stream>>>(pre4, rp, ci, nsrc, ndst, z4, N);     // z4
  k_up5<<<256, 512, 0, stream>>>(z1, z2, z3, z4, zlat, mlw, mlb, g5, pre5, N);
  k_spmm10<0><<<(N*10+255)/256, b256, 0, stream>>>(pre5, rp, ci, nsrc, ndst, hbuf, N);
  k_softmax10<<<(N+255)/256, b256, 0, stream>>>(hbuf, out_pred, N);
  // ---- clustering head ----
  k_q<<<(N+255)/256, b256, 0, stream>>>(zlat, cluster, out_q, colsum, N);
  k_p<<<(N+255)/256, b256, 0, stream>>>(out_q, colsum, out_p, N);

  // ---- decoder (z3/out_xbar slot free after k_up5) ----
  k_broad_reg<<<512, 512, 0, stream>>>(zlat, dw1, db1, xh, N, Mp, H3, 2048);             // dh1_h
  HGEMM(1,true, false,true,  xh,  dw2h, db2, (float*)nullptr, Ah2, 500, 512, 2048);      // dh2_h
  HGEMM(1,true, false,true,  Ah2, dw3h, db3, (float*)nullptr, Ah1, 500, 512, 512);       // dh3_h
  HGEMM(0,true, true, false, Ah1, xwh,  xb,  out_xbar, (_Float16*)nullptr, 2000, 2048, 512); // x_bar
  #undef HGEMM
}

// Round 4
// 2020.205 us; speedup vs baseline: 1.1994x; 1.1994x over previous
//
#include <hip/hip_runtime.h>
#include <cstdint>

typedef _Float16 half8 __attribute__((ext_vector_type(8)));
typedef _Float16 h2f __attribute__((ext_vector_type(2)));
typedef float f32x4 __attribute__((ext_vector_type(4)));

__device__ __forceinline__ float leakyf(float v){ return v > 0.f ? v : 0.01f*v; }
__device__ __forceinline__ float actf(float v, int act){
  if (act == 1) return fmaxf(v, 0.f);
  if (act == 2) return leakyf(v);
  return v;
}

__device__ __forceinline__ void gl_lds16(const void* g, void* l){
  __builtin_amdgcn_global_load_lds((const __attribute__((address_space(1))) void*)g,
                                   (__attribute__((address_space(3))) void*)l, 16, 0, 0);
}

// ---------------- graph build ----------------
__global__ void k_init_deg(int* deg_out, int* deg_in, int n){
  int i = blockIdx.x*blockDim.x + threadIdx.x;
  if (i < n){ deg_out[i] = 1; deg_in[i] = 1; }
}
__global__ void k_count(const int* __restrict__ src, const int* __restrict__ dst,
                        int* deg_out, int* deg_in, int e){
  int i = blockIdx.x*blockDim.x + threadIdx.x;
  if (i < e){ atomicAdd(&deg_out[src[i]], 1); atomicAdd(&deg_in[dst[i]], 1); }
}
__global__ void k_scan(const int* __restrict__ deg, int* rp, int n){
  __shared__ int sums[1024];
  int t = threadIdx.x;
  int per = (n + 1023)/1024;
  int base = t*per;
  int s = 0;
  for (int i = 0; i < per; ++i){ int j = base+i; if (j < n) s += deg[j]; }
  sums[t] = s; __syncthreads();
  for (int off = 1; off < 1024; off <<= 1){
    int v = 0;
    if (t >= off) v = sums[t-off];
    __syncthreads();
    if (t >= off) sums[t] += v;
    __syncthreads();
  }
  int run = (t == 0) ? 0 : sums[t-1];
  for (int i = 0; i < per; ++i){ int j = base+i; if (j < n){ rp[j] = run; run += deg[j]; } }
  if (t == 1023) rp[n] = sums[1023];
}
__global__ void k_zero_i(int* p, int n){ int i=blockIdx.x*blockDim.x+threadIdx.x; if(i<n) p[i]=0; }
__global__ void k_zero_f(float* p, int n){ int i=blockIdx.x*blockDim.x+threadIdx.x; if(i<n) p[i]=0.f; }
__global__ void k_fill(const int* __restrict__ src, const int* __restrict__ dst,
                       const int* __restrict__ rp, int* cursor, int* ci, int e, int n){
  int i = blockIdx.x*blockDim.x + threadIdx.x;
  if (i >= e + n) return;
  int s, d;
  if (i < e){ s = src[i]; d = dst[i]; } else { s = d = i - e; }
  int pos = atomicAdd(&cursor[d], 1);
  ci[rp[d] + pos] = s;
}
__global__ void k_norms(const int* deg_out, const int* deg_in, float* nsrc, float* ndst, int n){
  int i = blockIdx.x*blockDim.x + threadIdx.x;
  if (i < n){ nsrc[i] = rsqrtf((float)deg_out[i]); ndst[i] = rsqrtf((float)deg_in[i]); }
}

// ---------------- conversions ----------------
__global__ void k_conv_a(const float* __restrict__ in, _Float16* __restrict__ out,
                         int M, int K, int Mp, int Kp){
  long idx = (long)blockIdx.x*blockDim.x + threadIdx.x;
  long total = (long)Mp*(Kp/8);
  if (idx >= total) return;
  int kp8 = Kp/8;
  int m = (int)(idx / kp8);
  int k8 = (int)(idx % kp8) * 8;
  half8 o;
  #pragma unroll
  for (int j=0;j<8;++j){
    int k = k8+j;
    o[j] = (_Float16)((m<M && k<K) ? in[(size_t)m*K + k] : 0.f);
  }
  *(half8*)&out[(size_t)m*Kp + k8] = o;
}
__global__ void k_conv_bt(const float* __restrict__ in, _Float16* __restrict__ out,
                          int K, int N, int Np, int Kp){
  __shared__ float t[32][33];
  int kb = blockIdx.x*32, nb = blockIdx.y*32;
  int tx = threadIdx.x & 31, ty = threadIdx.x >> 5;
  for (int r=ty; r<32; r+=8){
    int k = kb+r, n = nb+tx;
    t[r][tx] = (k<K && n<N) ? in[(size_t)k*N+n] : 0.f;
  }
  __syncthreads();
  for (int r=ty; r<32; r+=8){
    int n = nb+r, k = kb+tx;
    if (n<Np && k<Kp) out[(size_t)n*Kp+k] = (_Float16)t[tx][r];
  }
}

// build Wc [128 x 3136] fp16: packed mlw + block-diag g5 over padded segment layout
// k in [0,512): seg0 real=k(<500); [512,1024): seg1 real=500+(k-512)(<500);
// [1024,3072): seg2 real=1000+(k-1024)(<2000); [3072,3136): kk=k-3072: kk<10 seg3 real=3000+kk;
// kk in [10,20) seg4 real=3010+kk-10; else pad.
__global__ void k_build_wc(const float* __restrict__ mlw, const float* __restrict__ g5,
                           _Float16* __restrict__ wc){
  int idx = blockIdx.x*blockDim.x + threadIdx.x;
  if (idx >= 128*3136) return;
  int c = idx / 3136, k = idx - (idx/3136)*3136;
  int seg = -1, real_k = 0;
  if (k < 512){ if (k < 500){ seg=0; real_k=k; } }
  else if (k < 1024){ int kk=k-512; if (kk<500){ seg=1; real_k=500+kk; } }
  else if (k < 3072){ int kk=k-1024; if (kk<2000){ seg=2; real_k=1000+kk; } }
  else { int kk=k-3072; if (kk<10){ seg=3; real_k=3000+kk; } else if (kk<20){ seg=4; real_k=3010+kk-10; } }
  float val = 0.f;
  if (seg >= 0){
    if (c < 5) val = mlw[(size_t)real_k*5 + c];
    else if (c < 55){ int t=c-5; if (t/10 == seg) val = g5[(size_t)real_k*10 + (t-(t/10)*10)]; }
  }
  wc[(size_t)c*3136 + k] = (_Float16)val;
}

// ---------------- fp16 MFMA GEMM: C = act(A @ B^T + bias) ----------------
template<int ACT, bool BIAS, bool F32OUT, bool F16OUT>
__global__ __launch_bounds__(256) void k_hgemm(
    const _Float16* __restrict__ A, const _Float16* __restrict__ BT,
    const float* __restrict__ bias, float* __restrict__ C, _Float16* __restrict__ Ch,
    int M, int Nvalid, long Np, long Kp)
{
  __shared__ __align__(16) _Float16 Asm[128*32];
  __shared__ __align__(16) _Float16 Bsm[128*32];
  const int m0 = blockIdx.y*128, n0 = blockIdx.x*128;
  const int tid = threadIdx.x;
  const int l = tid & 63, w = tid >> 6;
  const int wr = w >> 1, wc = w & 1;
  const int srow = tid >> 2, sseg = tid & 3;
  f32x4 acc[4][4] = {};

  for (long k0 = 0; k0 < Kp; k0 += 32){
    #pragma unroll
    for (int i=0;i<2;++i){
      int ar = i*64 + srow;
      gl_lds16(A  + (size_t)(m0+ar)*Kp + k0 + sseg*8, (char*)Asm + i*4096 + (size_t)tid*16);
      gl_lds16(BT + (size_t)(n0+ar)*Kp + k0 + sseg*8, (char*)Bsm + i*4096 + (size_t)tid*16);
    }
    __syncthreads();
    half8 af[4], bf[4];
    #pragma unroll
    for (int mi=0;mi<4;++mi)
      af[mi] = *(const half8*)&Asm[(size_t)(wr*64 + mi*16 + (l&15))*32 + (l>>4)*8];
    #pragma unroll
    for (int nj=0;nj<4;++nj)
      bf[nj] = *(const half8*)&Bsm[(size_t)(wc*64 + nj*16 + (l&15))*32 + (l>>4)*8];
    #pragma unroll
    for (int mi=0;mi<4;++mi)
      #pragma unroll
      for (int nj=0;nj<4;++nj)
        acc[mi][nj] = __builtin_amdgcn_mfma_f32_16x16x32_f16(af[mi], bf[nj], acc[mi][nj], 0,0,0);
    __syncthreads();
  }

  const int cr = (l>>4)*4, cc = l&15;
  #pragma unroll
  for (int mi=0;mi<4;++mi){
    #pragma unroll
    for (int nj=0;nj<4;++nj){
      int cbase = n0 + wc*64 + nj*16 + cc;
      bool cvalid = cbase < Nvalid;
      #pragma unroll
      for (int q=0;q<4;++q){
        int r = m0 + wr*64 + mi*16 + cr + q;
        float v = acc[mi][nj][q];
        if (BIAS && cvalid) v += bias[cbase];
        if (ACT==1) v = fmaxf(v,0.f); else if (ACT==2) v = leakyf(v);
        if (!cvalid) v = 0.f;
        if (F32OUT){ if (r < M && cvalid) C[(size_t)r*Nvalid + cbase] = v; }
        if (F16OUT){ Ch[(size_t)r*Np + cbase] = (_Float16)(r < M ? v : 0.f); }
      }
    }
  }
}

// ---------------- up5 GEMM: Y[Mp x 64] = segA @ Wc^T (segmented A) ----------------
__global__ __launch_bounds__(256) void k_hgemm_up5(
    const _Float16* __restrict__ z1h, const _Float16* __restrict__ z2h,
    const _Float16* __restrict__ z3h, const _Float16* __restrict__ z4zh,
    const _Float16* __restrict__ Wc, float* __restrict__ Y, int M)
{
  __shared__ __align__(16) _Float16 Asm[128*32];
  __shared__ __align__(16) _Float16 Bsm[128*32];
  const int m0 = blockIdx.y*128;
  const int tid = threadIdx.x;
  const int l = tid & 63, w = tid >> 6;
  const int wr = w >> 1, wc = w & 1;
  const int srow = tid >> 2, sseg = tid & 3;
  f32x4 acc[4][4] = {};

  for (int k0 = 0; k0 < 3136; k0 += 32){
    const _Float16* ab; long astr; int kk;
    if (k0 < 512){ ab=z1h; astr=512; kk=k0; }
    else if (k0 < 1024){ ab=z2h; astr=512; kk=k0-512; }
    else if (k0 < 3072){ ab=z3h; astr=2048; kk=k0-1024; }
    else { ab=z4zh; astr=64; kk=k0-3072; }
    #pragma unroll
    for (int i=0;i<2;++i){
      int ar = i*64 + srow;
      gl_lds16(ab + (size_t)(m0+ar)*astr + kk + sseg*8, (char*)Asm + i*4096 + (size_t)tid*16);
      gl_lds16(Wc + (size_t)ar*3136 + k0 + sseg*8, (char*)Bsm + i*4096 + (size_t)tid*16);
    }
    __syncthreads();
    half8 af[4], bf[4];
    #pragma unroll
    for (int mi=0;mi<4;++mi)
      af[mi] = *(const half8*)&Asm[(size_t)(wr*64 + mi*16 + (l&15))*32 + (l>>4)*8];
    #pragma unroll
    for (int nj=0;nj<4;++nj)
      bf[nj] = *(const half8*)&Bsm[(size_t)(wc*64 + nj*16 + (l&15))*32 + (l>>4)*8];
    #pragma unroll
    for (int mi=0;mi<4;++mi)
      #pragma unroll
      for (int nj=0;nj<4;++nj)
        acc[mi][nj] = __builtin_amdgcn_mfma_f32_16x16x32_f16(af[mi], bf[nj], acc[mi][nj], 0,0,0);
    __syncthreads();
  }

  const int cr = (l>>4)*4, cc = l&15;
  #pragma unroll
  for (int mi=0;mi<4;++mi){
    #pragma unroll
    for (int nj=0;nj<4;++nj){
      int cbase = wc*64 + nj*16 + cc;
      if (cbase >= 64) continue;
      #pragma unroll
      for (int q=0;q<4;++q){
        int r = m0 + wr*64 + mi*16 + cr + q;
        if (r < M) Y[(size_t)r*64 + cbase] = acc[mi][nj][q];
      }
    }
  }
}

// epilogue: u = l2(softmax(leaky(logits+mlb))); pre5 = sum_i u_i * P_i
__global__ void k_up5_fin(const float* __restrict__ Y, const float* __restrict__ mlb,
                          float* __restrict__ pre5, int M){
  int row = blockIdx.x*blockDim.x + threadIdx.x;
  if (row >= M) return;
  const float* y = Y + (size_t)row*64;
  float v[5]; float mx = -1e30f;
  #pragma unroll
  for (int c=0;c<5;++c){ float t = leakyf(y[c] + mlb[c]); v[c]=t; mx=fmaxf(mx,t); }
  float ss=0.f;
  #pragma unroll
  for (int c=0;c<5;++c){ v[c]=expf(v[c]-mx); ss += v[c]*v[c]; }
  float inv = rsqrtf(fmaxf(ss,1e-30f));
  #pragma unroll
  for (int c=0;c<5;++c) v[c] *= inv;
  #pragma unroll
  for (int c=0;c<10;++c){
    float s = 0.f;
    #pragma unroll
    for (int i=0;i<5;++i) s += v[i]*y[5 + 10*i + c];
    pre5[(size_t)row*10 + c] = s;
  }
}

// tail: z4zh[row][0:10]=z4, [10:20]=zlat, rest 0
__global__ void k_tail64(const float* __restrict__ z4, const float* __restrict__ zlat,
                         _Float16* __restrict__ z4zh, int M){
  int idx = blockIdx.x*blockDim.x + threadIdx.x;
  if (idx >= M*64) return;
  int row = idx >> 6, j = idx & 63;
  float v = 0.f;
  if (j < 10) v = z4[(size_t)row*10 + j];
  else if (j < 20) v = zlat[(size_t)row*10 + j - 10];
  z4zh[idx] = (_Float16)v;
}

// ---------------- skinny 10-out GEMM with LDS-staged transposed f32 weights ----------------
__global__ __launch_bounds__(256) void k_skinny10_lds(
    const float* __restrict__ A, long lda, const float* __restrict__ W, int K,
    const float* __restrict__ bias, float* __restrict__ out, int M, int act)
{
  __shared__ float wl[10*2048];
  int tid = threadIdx.x;
  for (int idx = tid; idx < K*10; idx += 256){
    int k = idx/10, c = idx - k*10;
    wl[c*K + k] = W[idx];
  }
  __syncthreads();
  int wv = tid >> 6, lane = tid & 63;
  int stride = gridDim.x*4;
  for (int row = blockIdx.x*4 + wv; row < M; row += stride){
    const float* a = A + (size_t)row*lda;
    float acc[10];
    #pragma unroll
    for (int c=0;c<10;++c) acc[c]=0.f;
    for (int k = lane; k < K; k += 64){
      float av = a[k];
      #pragma unroll
      for (int c=0;c<10;++c) acc[c] += av*wl[c*K + k];
    }
    #pragma unroll
    for (int c=0;c<10;++c){
      #pragma unroll
      for (int off=32; off; off>>=1) acc[c] += __shfl_down(acc[c], off);
    }
    if (lane == 0){
      #pragma unroll
      for (int c=0;c<10;++c){
        float v = acc[c] + (bias ? bias[c] : 0.f);
        out[(size_t)row*10 + c] = actf(v, act);
      }
    }
  }
}

// ---------------- decoder layer 1: weights in registers, rows looped ----------------
__global__ __launch_bounds__(512) void k_broad_reg(
    const float* __restrict__ Z, const float* __restrict__ W, const float* __restrict__ bias,
    _Float16* __restrict__ out, int M, int Mp, int Cc, int Cp)
{
  int tid = threadIdx.x;
  float wr[4][10], bv[4];
  #pragma unroll
  for (int j=0;j<4;++j){
    int c = tid + j*512;
    bool v = c < Cc;
    bv[j] = v ? bias[c] : 0.f;
    #pragma unroll
    for (int q=0;q<10;++q) wr[j][q] = v ? W[(size_t)q*Cc + c] : 0.f;
  }
  for (int row = blockIdx.x; row < Mp; row += gridDim.x){
    float zr[10];
    bool rv = row < M;
    #pragma unroll
    for (int q=0;q<10;++q) zr[q] = rv ? Z[(size_t)row*10 + q] : 0.f;
    #pragma unroll
    for (int j=0;j<4;++j){
      int c = tid + j*512;
      float v = bv[j];
      #pragma unroll
      for (int q=0;q<10;++q) v += zr[q]*wr[j][q];
      v = fmaxf(v, 0.f);
      out[(size_t)row*Cp + c] = (_Float16)((rv && c < Cc) ? v : 0.f);
    }
  }
}

// ---------------- fused gate + mix, fp16 out (padded) ----------------
__global__ void k_gate_mix_h(const float* __restrict__ tra, const float* __restrict__ zin,
                             const float* __restrict__ w, const float* __restrict__ b,
                             _Float16* __restrict__ mix, int W, int Wp)
{
  int row = blockIdx.x;
  int tid = threadIdx.x;
  const float* tr = tra + (size_t)row*W;
  const float* zr = zin + (size_t)row*W;
  float a0=0.f, a1=0.f;
  for (int k=tid; k<W; k+=256){ float t = tr[k]; a0 += t*w[2*k];       a1 += t*w[2*k+1]; }
  for (int k=tid; k<W; k+=256){ float zv = zr[k]; a0 += zv*w[2*(W+k)]; a1 += zv*w[2*(W+k)+1]; }
  #pragma unroll
  for (int off=32; off; off>>=1){ a0 += __shfl_down(a0,off); a1 += __shfl_down(a1,off); }
  __shared__ float red0[4], red1[4], m01[2];
  int wv = tid>>6, ln = tid&63;
  if (ln==0){ red0[wv]=a0; red1[wv]=a1; }
  __syncthreads();
  if (tid==0){
    float s0 = red0[0]+red0[1]+red0[2]+red0[3] + b[0];
    float s1 = red1[0]+red1[1]+red1[2]+red1[3] + b[1];
    s0 = leakyf(s0); s1 = leakyf(s1);
    float mx = fmaxf(s0,s1);
    float e0 = expf(s0-mx), e1 = expf(s1-mx);
    float inv = rsqrtf(fmaxf(e0*e0+e1*e1, 1e-30f));
    m01[0] = e0*inv; m01[1] = e1*inv;
  }
  __syncthreads();
  float mz = m01[0], mt = m01[1];
  for (int k=tid; k<W; k+=256){
    float t = tr[k], zv = zr[k];
    mix[(size_t)row*Wp + k] = (_Float16)(mz*zv + mt*t);
  }
  for (int k=W+tid; k<Wp; k+=256) mix[(size_t)row*Wp + k] = (_Float16)0.f;
}

// ---------------- fused gate + mix, f32 out in-place (stride W) ----------------
__global__ void k_gate_mix_f(const float* __restrict__ tra, const float* __restrict__ zin,
                             const float* __restrict__ w, const float* __restrict__ b,
                             float* __restrict__ mix, int W)
{
  int row = blockIdx.x;
  int tid = threadIdx.x;
  const float* tr = tra + (size_t)row*W;
  const float* zr = zin + (size_t)row*W;
  float a0=0.f, a1=0.f;
  for (int k=tid; k<W; k+=256){ float t = tr[k]; a0 += t*w[2*k];       a1 += t*w[2*k+1]; }
  for (int k=tid; k<W; k+=256){ float zv = zr[k]; a0 += zv*w[2*(W+k)]; a1 += zv*w[2*(W+k)+1]; }
  #pragma unroll
  for (int off=32; off; off>>=1){ a0 += __shfl_down(a0,off); a1 += __shfl_down(a1,off); }
  __shared__ float red0[4], red1[4], m01[2];
  int wv = tid>>6, ln = tid&63;
  if (ln==0){ red0[wv]=a0; red1[wv]=a1; }
  __syncthreads();
  if (tid==0){
    float s0 = red0[0]+red0[1]+red0[2]+red0[3] + b[0];
    float s1 = red1[0]+red1[1]+red1[2]+red1[3] + b[1];
    s0 = leakyf(s0); s1 = leakyf(s1);
    float mx = fmaxf(s0,s1);
    float e0 = expf(s0-mx), e1 = expf(s1-mx);
    float inv = rsqrtf(fmaxf(e0*e0+e1*e1, 1e-30f));
    m01[0] = e0*inv; m01[1] = e1*inv;
  }
  __syncthreads();
  float mz = m01[0], mt = m01[1];
  for (int k=tid; k<W; k+=256){
    float t = tr[k], zv = zr[k];
    mix[(size_t)row*W + k] = mz*zv + mt*t;
  }
}

// ---------------- SpMM gather, fp16x2 loads; optional f32 (stride W) + fp16 (stride Wp) out ----------------
template<int ACT, bool F32O, bool F16O>
__global__ void k_spmm2(const _Float16* __restrict__ h, const int* __restrict__ rp,
                        const int* __restrict__ ci, const float* __restrict__ nsrc,
                        const float* __restrict__ ndst, float* __restrict__ outf,
                        _Float16* __restrict__ outh, int W, int Wp)
{
  int row = blockIdx.x;
  int tid = threadIdx.x;          // 256 threads, 2 cols each
  int c = tid*2;
  int e0 = rp[row], e1 = rp[row+1];
  float a0=0.f, a1=0.f;
  for (int e=e0; e<e1; ++e){
    int s = ci[e];
    float ns = nsrc[s];
    h2f p = *(const h2f*)(h + (size_t)s*Wp + c);
    a0 += ns*(float)p[0];
    a1 += ns*(float)p[1];
  }
  float nd = ndst[row];
  a0 = actf(a0*nd, ACT); a1 = actf(a1*nd, ACT);
  if (F32O){
    if (c < W)   outf[(size_t)row*W + c]   = a0;
    if (c+1 < W) outf[(size_t)row*W + c+1] = a1;
  }
  if (F16O){
    h2f o;
    o[0] = (_Float16)(c   < W ? a0 : 0.f);
    o[1] = (_Float16)(c+1 < W ? a1 : 0.f);
    *(h2f*)(outh + (size_t)row*Wp + c) = o;
  }
}

// ---------------- SpMM gather, width 10 ----------------
template<int ACT>
__global__ void k_spmm10(const float* __restrict__ h, const int* __restrict__ rp,
                         const int* __restrict__ ci, const float* __restrict__ nsrc,
                         const float* __restrict__ ndst, float* __restrict__ out, int n)
{
  int idx = blockIdx.x*blockDim.x + threadIdx.x;
  if (idx >= n*10) return;
  int row = idx/10, c = idx - row*10;
  int e0 = rp[row], e1 = rp[row+1];
  float acc = 0.f;
  for (int e=e0; e<e1; ++e){
    int s = ci[e];
    acc += nsrc[s]*h[(size_t)s*10 + c];
  }
  out[idx] = actf(acc*ndst[row], ACT);
}

__global__ void k_softmax10(const float* __restrict__ h, float* __restrict__ out, int M){
  int row = blockIdx.x*blockDim.x + threadIdx.x;
  if (row >= M) return;
  float v[10]; float mx=-1e30f;
  #pragma unroll
  for (int j=0;j<10;++j){ v[j]=h[(size_t)row*10+j]; mx=fmaxf(mx,v[j]); }
  float s=0.f;
  #pragma unroll
  for (int j=0;j<10;++j){ v[j]=expf(v[j]-mx); s+=v[j]; }
  float inv=1.f/s;
  #pragma unroll
  for (int j=0;j<10;++j) out[(size_t)row*10+j]=v[j]*inv;
}

__global__ void k_q(const float* __restrict__ z, const float* __restrict__ cluster,
                    float* __restrict__ qout, float* __restrict__ colsum, int M)
{
  __shared__ float part[10];
  if (threadIdx.x < 10) part[threadIdx.x] = 0.f;
  __syncthreads();
  int row = blockIdx.x*blockDim.x + threadIdx.x;
  if (row < M){
    float zr[10];
    #pragma unroll
    for (int j=0;j<10;++j) zr[j] = z[(size_t)row*10+j];
    float qv[10]; float s=0.f;
    #pragma unroll
    for (int k=0;k<10;++k){
      float d2=0.f;
      #pragma unroll
      for (int j=0;j<10;++j){ float t = zr[j]-cluster[k*10+j]; d2 += t*t; }
      float qq = 1.f/(1.f+d2);
      qv[k]=qq; s+=qq;
    }
    float inv = 1.f/s;
    #pragma unroll
    for (int k=0;k<10;++k){
      float val = qv[k]*inv;
      qout[(size_t)row*10+k] = val;
      atomicAdd(&part[k], val);
    }
  }
  __syncthreads();
  if (threadIdx.x < 10) atomicAdd(&colsum[threadIdx.x], part[threadIdx.x]);
}

__global__ void k_p(const float* __restrict__ q, const float* __restrict__ colsum,
                    float* __restrict__ pout, int M){
  int row = blockIdx.x*blockDim.x + threadIdx.x;
  if (row >= M) return;
  float w[10]; float s=0.f;
  #pragma unroll
  for (int k=0;k<10;++k){ float qq=q[(size_t)row*10+k]; float ww=qq*qq/colsum[k]; w[k]=ww; s+=ww; }
  float inv=1.f/s;
  #pragma unroll
  for (int k=0;k<10;++k) pout[(size_t)row*10+k]=w[k]*inv;
}

extern "C" void kernel_launch(void* const* d_in, const int* in_sizes, int n_in,
                              void* d_out, int out_size, void* d_ws, size_t ws_size,
                              hipStream_t stream)
{
  const float* x   = (const float*)d_in[0];
  const float* ew1 = (const float*)d_in[1];  const float* eb1 = (const float*)d_in[2];
  const float* ew2 = (const float*)d_in[3];  const float* eb2 = (const float*)d_in[4];
  const float* ew3 = (const float*)d_in[5];  const float* eb3 = (const float*)d_in[6];
  const float* zw  = (const float*)d_in[7];  const float* zb  = (const float*)d_in[8];
  const float* dw1 = (const float*)d_in[9];  const float* db1 = (const float*)d_in[10];
  const float* dw2 = (const float*)d_in[11]; const float* db2 = (const float*)d_in[12];
  const float* dw3 = (const float*)d_in[13]; const float* db3 = (const float*)d_in[14];
  const float* xw  = (const float*)d_in[15]; const float* xb  = (const float*)d_in[16];
  const float* g1  = (const float*)d_in[17];
  const float* g2  = (const float*)d_in[18];
  const float* g3  = (const float*)d_in[19];
  const float* g4  = (const float*)d_in[20];
  const float* g5  = (const float*)d_in[21];
  const float* m1w = (const float*)d_in[22]; const float* m1b = (const float*)d_in[23];
  const float* m2w = (const float*)d_in[24]; const float* m2b = (const float*)d_in[25];
  const float* m3w = (const float*)d_in[26]; const float* m3b = (const float*)d_in[27];
  const float* mlw = (const float*)d_in[28]; const float* mlb = (const float*)d_in[29];
  const float* cluster = (const float*)d_in[30];
  const int* src = (const int*)d_in[31];
  const int* dst = (const int*)d_in[32];

  const int NI=2000, H1=500, H2=500, H3=2000;
  const int N = in_sizes[0] / NI;      // 20000
  const int E = in_sizes[31];          // 320000
  const int M_tot = E + N;
  const int Mp = ((N + 127)/128)*128;  // 20096

  float* out = (float*)d_out;
  float* out_xbar = out;
  float* out_q    = out + (size_t)N*NI;
  float* out_pred = out_q + (size_t)N*10;
  float* out_p    = out_pred + (size_t)N*10;

  // ---- workspace carve ----
  char* base = (char*)d_ws;
  size_t off = 0;
  auto AF = [&](size_t e)->float*{ float* r=(float*)(base+off); off += ((e*sizeof(float)+15)&~(size_t)15); return r; };
  auto AI = [&](size_t e)->int*  { int*   r=(int*)  (base+off); off += ((e*sizeof(int)  +15)&~(size_t)15); return r; };
  auto AH = [&](size_t e)->_Float16*{ _Float16* r=(_Float16*)(base+off); off += ((e*sizeof(_Float16)+15)&~(size_t)15); return r; };

  int* deg_out = AI(N); int* deg_in = AI(N);
  int* rp = AI(N+1); int* cursor = AI(N); int* ci = AI(M_tot);
  float* nsrc = AF(N); float* ndst = AF(N); float* colsum = AF(16);
  float* tra1 = AF((size_t)N*H1);
  float* tra2 = AF((size_t)N*H2);
  float* tra3 = AF((size_t)N*H3);   // -> mix3 f32 in place
  float* zlat = AF((size_t)N*10);
  float* z1   = AF((size_t)N*H1);
  float* z2   = AF((size_t)N*H2);
  float* z3   = out_xbar;           // N*2000 f32 in x_bar slot (dead before decoder final GEMM)
  float* pre4 = AF((size_t)N*10);
  float* z4   = AF((size_t)N*10);
  float* pre5 = AF((size_t)N*10);
  float* hbuf = AF((size_t)N*10);
  float* Ybuf = AF((size_t)Mp*64);
  // fp16 buffers
  _Float16* xh   = AH((size_t)Mp*2048);  // x_h -> z3_h -> dh1_h
  _Float16* Ah1  = AH((size_t)Mp*512);   // tra1_h -> pre1_h -> agg2_h -> agg3_h -> dh3_h
  _Float16* Ah2  = AH((size_t)Mp*512);   // tra2_h -> mix1_h -> mix2_h -> dh2_h
  _Float16* z1h  = AH((size_t)Mp*512);
  _Float16* z2h  = AH((size_t)Mp*512);
  _Float16* z4zh = AH((size_t)Mp*64);
  _Float16* wch  = AH((size_t)128*3136);
  _Float16* ew1h = AH((size_t)512*2048);
  _Float16* ew2h = AH((size_t)512*512);
  _Float16* ew3h = AH((size_t)2048*512);
  _Float16* dw2h = AH((size_t)512*2048);
  _Float16* dw3h = AH((size_t)512*512);
  _Float16* xwh  = AH((size_t)2048*512);
  _Float16* g1h  = AH((size_t)512*2048);
  _Float16* g2h  = AH((size_t)512*512);
  _Float16* g3h  = AH((size_t)2048*512);
  (void)ws_size; (void)out_size; (void)n_in;

  dim3 b256(256);
  // ---- graph build ----
  k_init_deg<<<(N+255)/256, b256, 0, stream>>>(deg_out, deg_in, N);
  k_count<<<(E+255)/256, b256, 0, stream>>>(src, dst, deg_out, deg_in, E);
  k_scan<<<1, 1024, 0, stream>>>(deg_in, rp, N);
  k_zero_i<<<(N+255)/256, b256, 0, stream>>>(cursor, N);
  k_zero_f<<<1, 64, 0, stream>>>(colsum, 16);
  k_fill<<<(M_tot+255)/256, b256, 0, stream>>>(src, dst, rp, cursor, ci, E, N);
  k_norms<<<(N+255)/256, b256, 0, stream>>>(deg_out, deg_in, nsrc, ndst, N);

  // ---- conversions ----
  {
    long tot = (long)Mp*(2048/8);
    k_conv_a<<<(tot+255)/256, b256, 0, stream>>>(x, xh, N, NI, Mp, 2048);
  }
  #define CONVBT(W_, K_, N_, NP_, KP_, OUT_) \
    k_conv_bt<<<dim3((KP_)/32,(NP_)/32), b256, 0, stream>>>((W_), (OUT_), (K_), (N_), (NP_), (KP_))
  CONVBT(ew1, 2000, 500, 512, 2048, ew1h);
  CONVBT(ew2, 500, 500, 512, 512, ew2h);
  CONVBT(ew3, 500, 2000, 2048, 512, ew3h);
  CONVBT(dw2, 2000, 500, 512, 2048, dw2h);
  CONVBT(dw3, 500, 500, 512, 512, dw3h);
  CONVBT(xw,  500, 2000, 2048, 512, xwh);
  CONVBT(g1,  2000, 500, 512, 2048, g1h);
  CONVBT(g2,  500, 500, 512, 512, g2h);
  CONVBT(g3,  500, 2000, 2048, 512, g3h);
  #undef CONVBT
  k_build_wc<<<(128*3136+255)/256, b256, 0, stream>>>(mlw, g5, wch);

  const int MT = Mp/128;   // 157
  #define HGEMM(ACT,BIAS,F32O,F16O, A_,BT_,BIASP_,C_,CH_, NV_,NP_,KP_) \
    k_hgemm<ACT,BIAS,F32O,F16O><<<dim3((NP_)/128, MT), b256, 0, stream>>>( \
      (A_),(BT_),(BIASP_),(C_),(CH_), N, (NV_), (NP_), (KP_))

  // ---- encoder ----
  HGEMM(1,true, true, true,  xh,  ew1h, eb1, tra1, Ah1, 500, 512, 2048);   // tra1 + tra1_h
  HGEMM(1,true, true, true,  Ah1, ew2h, eb2, tra2, Ah2, 500, 512, 512);    // tra2 + tra2_h
  HGEMM(1,true, true, false, Ah2, ew3h, eb3, tra3, (_Float16*)nullptr, 2000, 2048, 512); // tra3
  k_skinny10_lds<<<512, b256, 0, stream>>>(tra3, 2000, zw, 2000, zb, zlat, N, 0);

  // ---- GCN branch ----
  HGEMM(0,false,false,true,  xh,  g1h, nullptr, (float*)nullptr, Ah1, 500, 512, 2048);     // pre1_h
  k_spmm2<2,true,true><<<N, b256, 0, stream>>>(Ah1, rp, ci, nsrc, ndst, z1, z1h, H1, 512); // z1 + z1h
  k_gate_mix_h<<<N, b256, 0, stream>>>(tra1, z1, m1w, m1b, Ah2, H1, 512);                  // mix1_h
  k_spmm2<0,false,true><<<N, b256, 0, stream>>>(Ah2, rp, ci, nsrc, ndst, (float*)nullptr, Ah1, H1, 512); // agg2_h
  HGEMM(2,false,true, true,  Ah1, g2h, nullptr, z2, z2h, 500, 512, 512);                   // z2 + z2h
  k_gate_mix_h<<<N, b256, 0, stream>>>(tra2, z2, m2w, m2b, Ah2, H2, 512);                  // mix2_h
  k_spmm2<0,false,true><<<N, b256, 0, stream>>>(Ah2, rp, ci, nsrc, ndst, (float*)nullptr, Ah1, H2, 512); // agg3_h
  HGEMM(2,false,true, true,  Ah1, g3h, nullptr, z3, xh, 2000, 2048, 512);                  // z3 + z3h (xh)
  k_gate_mix_f<<<N, b256, 0, stream>>>(tra3, z3, m3w, m3b, tra3, H3);                      // mix3 f32 in place
  k_skinny10_lds<<<512, b256, 0, stream>>>(tra3, 2000, g4, 2000, nullptr, pre4, N, 0);
  k_spmm10<2><<<(N*10+255)/256, b256, 0, stream>>>(pre4, rp, ci, nsrc, ndst, z4, N);       // z4
  k_tail64<<<(N*64+255)/256, b256, 0, stream>>>(z4, zlat, z4zh, N);
  k_hgemm_up5<<<dim3(1, MT), b256, 0, stream>>>(z1h, z2h, xh, z4zh, wch, Ybuf, N);
  k_up5_fin<<<(N+255)/256, b256, 0, stream>>>(Ybuf, mlb, pre5, N);
  k_spmm10<0><<<(N*10+255)/256, b256, 0, stream>>>(pre5, rp, ci, nsrc, ndst, hbuf, N);
  k_softmax10<<<(N+255)/256, b256, 0, stream>>>(hbuf, out_pred, N);
  // ---- clustering head ----
  k_q<<<(N+255)/256, b256, 0, stream>>>(zlat, cluster, out_q, colsum, N);
  k_p<<<(N+255)/256, b256, 0, stream>>>(out_q, colsum, out_p, N);

  // ---- decoder (z3/out_xbar and xh free now) ----
  k_broad_reg<<<512, 512, 0, stream>>>(zlat, dw1, db1, xh, N, Mp, H3, 2048);               // dh1_h
  HGEMM(1,true, false,true,  xh,  dw2h, db2, (float*)nullptr, Ah2, 500, 512, 2048);        // dh2_h
  HGEMM(1,true, false,true,  Ah2, dw3h, db3, (float*)nullptr, Ah1, 500, 512, 512);         // dh3_h
  HGEMM(0,true, true, false, Ah1, xwh,  xb,  out_xbar, (_Float16*)nullptr, 2000, 2048, 512); // x_bar
  #undef HGEMM
}

// Round 5
// 1761.124 us; speedup vs baseline: 1.3758x; 1.1471x over previous
//
#include <hip/hip_runtime.h>
#include <cstdint>

typedef _Float16 half8 __attribute__((ext_vector_type(8)));
typedef _Float16 h2f __attribute__((ext_vector_type(2)));
typedef float f32x4 __attribute__((ext_vector_type(4)));

__device__ __forceinline__ float leakyf(float v){ return v > 0.f ? v : 0.01f*v; }
__device__ __forceinline__ float actf(float v, int act){
  if (act == 1) return fmaxf(v, 0.f);
  if (act == 2) return leakyf(v);
  return v;
}

__device__ __forceinline__ void gl_lds16(const void* g, void* l){
  __builtin_amdgcn_global_load_lds((const __attribute__((address_space(1))) void*)g,
                                   (__attribute__((address_space(3))) void*)l, 16, 0, 0);
}

// ---------------- graph build ----------------
__global__ void k_init_deg(int* deg_out, int* deg_in, int n){
  int i = blockIdx.x*blockDim.x + threadIdx.x;
  if (i < n){ deg_out[i] = 1; deg_in[i] = 1; }
}
__global__ void k_count(const int* __restrict__ src, const int* __restrict__ dst,
                        int* deg_out, int* deg_in, int e){
  int i = blockIdx.x*blockDim.x + threadIdx.x;
  if (i < e){ atomicAdd(&deg_out[src[i]], 1); atomicAdd(&deg_in[dst[i]], 1); }
}
__global__ void k_scan(const int* __restrict__ deg, int* rp, int n){
  __shared__ int sums[1024];
  int t = threadIdx.x;
  int per = (n + 1023)/1024;
  int base = t*per;
  int s = 0;
  for (int i = 0; i < per; ++i){ int j = base+i; if (j < n) s += deg[j]; }
  sums[t] = s; __syncthreads();
  for (int off = 1; off < 1024; off <<= 1){
    int v = 0;
    if (t >= off) v = sums[t-off];
    __syncthreads();
    if (t >= off) sums[t] += v;
    __syncthreads();
  }
  int run = (t == 0) ? 0 : sums[t-1];
  for (int i = 0; i < per; ++i){ int j = base+i; if (j < n){ rp[j] = run; run += deg[j]; } }
  if (t == 1023) rp[n] = sums[1023];
}
__global__ void k_zero_i(int* p, int n){ int i=blockIdx.x*blockDim.x+threadIdx.x; if(i<n) p[i]=0; }
__global__ void k_zero_f(float* p, int n){ int i=blockIdx.x*blockDim.x+threadIdx.x; if(i<n) p[i]=0.f; }
__global__ void k_fill(const int* __restrict__ src, const int* __restrict__ dst,
                       const int* __restrict__ rp, int* cursor, int* ci, int e, int n){
  int i = blockIdx.x*blockDim.x + threadIdx.x;
  if (i >= e + n) return;
  int s, d;
  if (i < e){ s = src[i]; d = dst[i]; } else { s = d = i - e; }
  int pos = atomicAdd(&cursor[d], 1);
  ci[rp[d] + pos] = s;
}
__global__ void k_norms(const int* deg_out, const int* deg_in, float* nsrc, float* ndst, int n){
  int i = blockIdx.x*blockDim.x + threadIdx.x;
  if (i < n){ nsrc[i] = rsqrtf((float)deg_out[i]); ndst[i] = rsqrtf((float)deg_in[i]); }
}

// ---------------- conversions ----------------
__global__ void k_conv_a(const float* __restrict__ in, _Float16* __restrict__ out,
                         int M, int K, int Mp, int Kp){
  long idx = (long)blockIdx.x*blockDim.x + threadIdx.x;
  long total = (long)Mp*(Kp/8);
  if (idx >= total) return;
  int kp8 = Kp/8;
  int m = (int)(idx / kp8);
  int k8 = (int)(idx % kp8) * 8;
  half8 o;
  #pragma unroll
  for (int j=0;j<8;++j){
    int k = k8+j;
    o[j] = (_Float16)((m<M && k<K) ? in[(size_t)m*K + k] : 0.f);
  }
  *(half8*)&out[(size_t)m*Kp + k8] = o;
}
__global__ void k_conv_bt(const float* __restrict__ in, _Float16* __restrict__ out,
                          int K, int N, int Np, int Kp){
  __shared__ float t[32][33];
  int kb = blockIdx.x*32, nb = blockIdx.y*32;
  int tx = threadIdx.x & 31, ty = threadIdx.x >> 5;
  for (int r=ty; r<32; r+=8){
    int k = kb+r, n = nb+tx;
    t[r][tx] = (k<K && n<N) ? in[(size_t)k*N+n] : 0.f;
  }
  __syncthreads();
  for (int r=ty; r<32; r+=8){
    int n = nb+r, k = kb+tx;
    if (n<Np && k<Kp) out[(size_t)n*Kp+k] = (_Float16)t[tx][r];
  }
}

// build Wc [128 x 3136] fp16: packed mlw + block-diag g5 over padded segment layout
__global__ void k_build_wc(const float* __restrict__ mlw, const float* __restrict__ g5,
                           _Float16* __restrict__ wc){
  int idx = blockIdx.x*blockDim.x + threadIdx.x;
  if (idx >= 128*3136) return;
  int c = idx / 3136, k = idx - (idx/3136)*3136;
  int seg = -1, real_k = 0;
  if (k < 512){ if (k < 500){ seg=0; real_k=k; } }
  else if (k < 1024){ int kk=k-512; if (kk<500){ seg=1; real_k=500+kk; } }
  else if (k < 3072){ int kk=k-1024; if (kk<2000){ seg=2; real_k=1000+kk; } }
  else { int kk=k-3072; if (kk<10){ seg=3; real_k=3000+kk; } else if (kk<20){ seg=4; real_k=3010+kk-10; } }
  float val = 0.f;
  if (seg >= 0){
    if (c < 5) val = mlw[(size_t)real_k*5 + c];
    else if (c < 55){ int t=c-5; if (t/10 == seg) val = g5[(size_t)real_k*10 + (t-(t/10)*10)]; }
  }
  wc[(size_t)c*3136 + k] = (_Float16)val;
}

// ---------------- fp16 MFMA GEMM: C = act(A @ B^T + bias) ----------------
template<int ACT, bool BIAS, bool F32OUT, bool F16OUT>
__global__ __launch_bounds__(256) void k_hgemm(
    const _Float16* __restrict__ A, const _Float16* __restrict__ BT,
    const float* __restrict__ bias, float* __restrict__ C, _Float16* __restrict__ Ch,
    int M, int Nvalid, long Np, long Kp)
{
  __shared__ __align__(16) _Float16 Asm[128*32];
  __shared__ __align__(16) _Float16 Bsm[128*32];
  const int m0 = blockIdx.y*128, n0 = blockIdx.x*128;
  const int tid = threadIdx.x;
  const int l = tid & 63, w = tid >> 6;
  const int wr = w >> 1, wc = w & 1;
  const int srow = tid >> 2, sseg = tid & 3;
  f32x4 acc[4][4] = {};

  for (long k0 = 0; k0 < Kp; k0 += 32){
    #pragma unroll
    for (int i=0;i<2;++i){
      int ar = i*64 + srow;
      gl_lds16(A  + (size_t)(m0+ar)*Kp + k0 + sseg*8, (char*)Asm + i*4096 + (size_t)tid*16);
      gl_lds16(BT + (size_t)(n0+ar)*Kp + k0 + sseg*8, (char*)Bsm + i*4096 + (size_t)tid*16);
    }
    __syncthreads();
    half8 af[4], bf[4];
    #pragma unroll
    for (int mi=0;mi<4;++mi)
      af[mi] = *(const half8*)&Asm[(size_t)(wr*64 + mi*16 + (l&15))*32 + (l>>4)*8];
    #pragma unroll
    for (int nj=0;nj<4;++nj)
      bf[nj] = *(const half8*)&Bsm[(size_t)(wc*64 + nj*16 + (l&15))*32 + (l>>4)*8];
    #pragma unroll
    for (int mi=0;mi<4;++mi)
      #pragma unroll
      for (int nj=0;nj<4;++nj)
        acc[mi][nj] = __builtin_amdgcn_mfma_f32_16x16x32_f16(af[mi], bf[nj], acc[mi][nj], 0,0,0);
    __syncthreads();
  }

  const int cr = (l>>4)*4, cc = l&15;
  #pragma unroll
  for (int mi=0;mi<4;++mi){
    #pragma unroll
    for (int nj=0;nj<4;++nj){
      int cbase = n0 + wc*64 + nj*16 + cc;
      bool cvalid = cbase < Nvalid;
      #pragma unroll
      for (int q=0;q<4;++q){
        int r = m0 + wr*64 + mi*16 + cr + q;
        float v = acc[mi][nj][q];
        if (BIAS && cvalid) v += bias[cbase];
        if (ACT==1) v = fmaxf(v,0.f); else if (ACT==2) v = leakyf(v);
        if (!cvalid) v = 0.f;
        if (F32OUT){ if (r < M && cvalid) C[(size_t)r*Nvalid + cbase] = v; }
        if (F16OUT){ Ch[(size_t)r*Np + cbase] = (_Float16)(r < M ? v : 0.f); }
      }
    }
  }
}

// ---------------- up5 GEMM: Y[Mp x 64] = segA @ Wc^T (segmented A) ----------------
__global__ __launch_bounds__(256) void k_hgemm_up5(
    const _Float16* __restrict__ z1h, const _Float16* __restrict__ z2h,
    const _Float16* __restrict__ z3h, const _Float16* __restrict__ z4zh,
    const _Float16* __restrict__ Wc, float* __restrict__ Y, int M)
{
  __shared__ __align__(16) _Float16 Asm[128*32];
  __shared__ __align__(16) _Float16 Bsm[128*32];
  const int m0 = blockIdx.y*128;
  const int tid = threadIdx.x;
  const int l = tid & 63, w = tid >> 6;
  const int wr = w >> 1, wc = w & 1;
  const int srow = tid >> 2, sseg = tid & 3;
  f32x4 acc[4][4] = {};

  for (int k0 = 0; k0 < 3136; k0 += 32){
    const _Float16* ab; long astr; int kk;
    if (k0 < 512){ ab=z1h; astr=512; kk=k0; }
    else if (k0 < 1024){ ab=z2h; astr=512; kk=k0-512; }
    else if (k0 < 3072){ ab=z3h; astr=2048; kk=k0-1024; }
    else { ab=z4zh; astr=64; kk=k0-3072; }
    #pragma unroll
    for (int i=0;i<2;++i){
      int ar = i*64 + srow;
      gl_lds16(ab + (size_t)(m0+ar)*astr + kk + sseg*8, (char*)Asm + i*4096 + (size_t)tid*16);
      gl_lds16(Wc + (size_t)ar*3136 + k0 + sseg*8, (char*)Bsm + i*4096 + (size_t)tid*16);
    }
    __syncthreads();
    half8 af[4], bf[4];
    #pragma unroll
    for (int mi=0;mi<4;++mi)
      af[mi] = *(const half8*)&Asm[(size_t)(wr*64 + mi*16 + (l&15))*32 + (l>>4)*8];
    #pragma unroll
    for (int nj=0;nj<4;++nj)
      bf[nj] = *(const half8*)&Bsm[(size_t)(wc*64 + nj*16 + (l&15))*32 + (l>>4)*8];
    #pragma unroll
    for (int mi=0;mi<4;++mi)
      #pragma unroll
      for (int nj=0;nj<4;++nj)
        acc[mi][nj] = __builtin_amdgcn_mfma_f32_16x16x32_f16(af[mi], bf[nj], acc[mi][nj], 0,0,0);
    __syncthreads();
  }

  const int cr = (l>>4)*4, cc = l&15;
  #pragma unroll
  for (int mi=0;mi<4;++mi){
    #pragma unroll
    for (int nj=0;nj<4;++nj){
      int cbase = wc*64 + nj*16 + cc;
      if (cbase >= 64) continue;
      #pragma unroll
      for (int q=0;q<4;++q){
        int r = m0 + wr*64 + mi*16 + cr + q;
        if (r < M) Y[(size_t)r*64 + cbase] = acc[mi][nj][q];
      }
    }
  }
}

// epilogue: u = l2(softmax(leaky(logits+mlb))); pre5 = sum_i u_i * P_i
__global__ void k_up5_fin(const float* __restrict__ Y, const float* __restrict__ mlb,
                          float* __restrict__ pre5, int M){
  int row = blockIdx.x*blockDim.x + threadIdx.x;
  if (row >= M) return;
  const float* y = Y + (size_t)row*64;
  float v[5]; float mx = -1e30f;
  #pragma unroll
  for (int c=0;c<5;++c){ float t = leakyf(y[c] + mlb[c]); v[c]=t; mx=fmaxf(mx,t); }
  float ss=0.f;
  #pragma unroll
  for (int c=0;c<5;++c){ v[c]=expf(v[c]-mx); ss += v[c]*v[c]; }
  float inv = rsqrtf(fmaxf(ss,1e-30f));
  #pragma unroll
  for (int c=0;c<5;++c) v[c] *= inv;
  #pragma unroll
  for (int c=0;c<10;++c){
    float s = 0.f;
    #pragma unroll
    for (int i=0;i<5;++i) s += v[i]*y[5 + 10*i + c];
    pre5[(size_t)row*10 + c] = s;
  }
}

// tail: z4zh[row][0:10]=z4, [10:20]=zlat, rest 0
__global__ void k_tail64(const float* __restrict__ z4, const float* __restrict__ zlat,
                         _Float16* __restrict__ z4zh, int M){
  int idx = blockIdx.x*blockDim.x + threadIdx.x;
  if (idx >= M*64) return;
  int row = idx >> 6, j = idx & 63;
  float v = 0.f;
  if (j < 10) v = z4[(size_t)row*10 + j];
  else if (j < 20) v = zlat[(size_t)row*10 + j - 10];
  z4zh[idx] = (_Float16)v;
}

// ---------------- skinny 10-out GEMM, fp16 A, LDS-staged transposed f32 weights ----------------
__global__ __launch_bounds__(256) void k_skinny10_h(
    const _Float16* __restrict__ A, long lda, const float* __restrict__ W, int K,
    const float* __restrict__ bias, float* __restrict__ out, int M, int act)
{
  __shared__ float wl[10*2000];
  int tid = threadIdx.x;
  for (int idx = tid; idx < K*10; idx += 256){
    int k = idx/10, c = idx - k*10;
    wl[c*K + k] = W[idx];
  }
  __syncthreads();
  int wv = tid >> 6, lane = tid & 63;
  int stride = gridDim.x*4;
  for (int row = blockIdx.x*4 + wv; row < M; row += stride){
    const _Float16* a = A + (size_t)row*lda;
    float acc[10];
    #pragma unroll
    for (int c=0;c<10;++c) acc[c]=0.f;
    for (int k0 = lane*2; k0 < K; k0 += 128){
      h2f t2 = *(const h2f*)(a + k0);
      float v0 = (float)t2[0], v1 = (float)t2[1];
      #pragma unroll
      for (int c=0;c<10;++c) acc[c] += v0*wl[c*K + k0] + v1*wl[c*K + k0 + 1];
    }
    #pragma unroll
    for (int c=0;c<10;++c){
      #pragma unroll
      for (int off=32; off; off>>=1) acc[c] += __shfl_down(acc[c], off);
    }
    if (lane == 0){
      #pragma unroll
      for (int c=0;c<10;++c){
        float v = acc[c] + (bias ? bias[c] : 0.f);
        out[(size_t)row*10 + c] = actf(v, act);
      }
    }
  }
}

// ---------------- fused mix + skinny10: pre4 = (mz*z3 + mt*tra3) @ g4 ----------------
__global__ __launch_bounds__(256) void k_skinny10_mix(
    const _Float16* __restrict__ tra, const _Float16* __restrict__ zin, long lda,
    const float* __restrict__ gm, const float* __restrict__ W, int K,
    float* __restrict__ out, int M)
{
  __shared__ float wl[10*2000];
  int tid = threadIdx.x;
  for (int idx = tid; idx < K*10; idx += 256){
    int k = idx/10, c = idx - k*10;
    wl[c*K + k] = W[idx];
  }
  __syncthreads();
  int wv = tid >> 6, lane = tid & 63;
  int stride = gridDim.x*4;
  for (int row = blockIdx.x*4 + wv; row < M; row += stride){
    const _Float16* tr = tra + (size_t)row*lda;
    const _Float16* zr = zin + (size_t)row*lda;
    float mz = gm[row*2], mt = gm[row*2+1];
    float acc[10];
    #pragma unroll
    for (int c=0;c<10;++c) acc[c]=0.f;
    for (int k0 = lane*2; k0 < K; k0 += 128){
      h2f t2 = *(const h2f*)(tr + k0);
      h2f z2 = *(const h2f*)(zr + k0);
      float v0 = mz*(float)z2[0] + mt*(float)t2[0];
      float v1 = mz*(float)z2[1] + mt*(float)t2[1];
      #pragma unroll
      for (int c=0;c<10;++c) acc[c] += v0*wl[c*K + k0] + v1*wl[c*K + k0 + 1];
    }
    #pragma unroll
    for (int c=0;c<10;++c){
      #pragma unroll
      for (int off=32; off; off>>=1) acc[c] += __shfl_down(acc[c], off);
    }
    if (lane == 0){
      #pragma unroll
      for (int c=0;c<10;++c) out[(size_t)row*10 + c] = acc[c];
    }
  }
}

// ---------------- gate coefficients only (W=2000, Wp=2048): gm[row]={mz,mt} ----------------
__global__ void k_gate_coef_h(const _Float16* __restrict__ tra, const _Float16* __restrict__ zin,
                              const float* __restrict__ w, const float* __restrict__ b,
                              float* __restrict__ gm, int W, long Wp)
{
  int row = blockIdx.x;
  int tid = threadIdx.x;
  const _Float16* tr = tra + (size_t)row*Wp;
  const _Float16* zr = zin + (size_t)row*Wp;
  float a0=0.f, a1=0.f;
  int k0 = tid*8;
  if (k0 < Wp){
    half8 t8 = *(const half8*)(tr + k0);
    half8 z8 = *(const half8*)(zr + k0);
    #pragma unroll
    for (int j=0;j<8;++j){
      int k = k0 + j;
      if (k < W){
        float t = (float)t8[j], zv = (float)z8[j];
        a0 += t*w[2*k]   + zv*w[2*(W+k)];
        a1 += t*w[2*k+1] + zv*w[2*(W+k)+1];
      }
    }
  }
  #pragma unroll
  for (int off=32; off; off>>=1){ a0 += __shfl_down(a0,off); a1 += __shfl_down(a1,off); }
  __shared__ float red0[4], red1[4];
  int wv = tid>>6, ln = tid&63;
  if (ln==0){ red0[wv]=a0; red1[wv]=a1; }
  __syncthreads();
  if (tid==0){
    float s0 = red0[0]+red0[1]+red0[2]+red0[3] + b[0];
    float s1 = red1[0]+red1[1]+red1[2]+red1[3] + b[1];
    s0 = leakyf(s0); s1 = leakyf(s1);
    float mx = fmaxf(s0,s1);
    float e0 = expf(s0-mx), e1 = expf(s1-mx);
    float inv = rsqrtf(fmaxf(e0*e0+e1*e1, 1e-30f));
    gm[row*2+0] = e0*inv;   // z coefficient
    gm[row*2+1] = e1*inv;   // tra coefficient
  }
}

// ---------------- fused gate+mix, fp16 in/out (W=500, Wp=512) ----------------
__global__ void k_gate_mix_hh(const _Float16* __restrict__ tra, const _Float16* __restrict__ zin,
                              const float* __restrict__ w, const float* __restrict__ b,
                              _Float16* __restrict__ mix, int W, int Wp)
{
  int row = blockIdx.x;
  int tid = threadIdx.x;
  const _Float16* tr = tra + (size_t)row*Wp;
  const _Float16* zr = zin + (size_t)row*Wp;
  int c = tid*2;
  h2f t2 = *(const h2f*)(tr + c);
  h2f z2 = *(const h2f*)(zr + c);
  float a0=0.f, a1=0.f;
  #pragma unroll
  for (int j=0;j<2;++j){
    int k = c + j;
    if (k < W){
      float t = (float)t2[j], zv = (float)z2[j];
      a0 += t*w[2*k]   + zv*w[2*(W+k)];
      a1 += t*w[2*k+1] + zv*w[2*(W+k)+1];
    }
  }
  #pragma unroll
  for (int off=32; off; off>>=1){ a0 += __shfl_down(a0,off); a1 += __shfl_down(a1,off); }
  __shared__ float red0[4], red1[4], m01[2];
  int wv = tid>>6, ln = tid&63;
  if (ln==0){ red0[wv]=a0; red1[wv]=a1; }
  __syncthreads();
  if (tid==0){
    float s0 = red0[0]+red0[1]+red0[2]+red0[3] + b[0];
    float s1 = red1[0]+red1[1]+red1[2]+red1[3] + b[1];
    s0 = leakyf(s0); s1 = leakyf(s1);
    float mx = fmaxf(s0,s1);
    float e0 = expf(s0-mx), e1 = expf(s1-mx);
    float inv = rsqrtf(fmaxf(e0*e0+e1*e1, 1e-30f));
    m01[0] = e0*inv; m01[1] = e1*inv;
  }
  __syncthreads();
  float mz = m01[0], mt = m01[1];
  h2f o;
  #pragma unroll
  for (int j=0;j<2;++j){
    int k = c + j;
    o[j] = (_Float16)(k < W ? (mz*(float)z2[j] + mt*(float)t2[j]) : 0.f);
  }
  *(h2f*)(mix + (size_t)row*Wp + c) = o;
}

// ---------------- SpMM gather, fp16x2 loads; fp16 out (stride Wp) ----------------
template<int ACT>
__global__ void k_spmm2(const _Float16* __restrict__ h, const int* __restrict__ rp,
                        const int* __restrict__ ci, const float* __restrict__ nsrc,
                        const float* __restrict__ ndst, _Float16* __restrict__ outh,
                        int W, int Wp)
{
  int row = blockIdx.x;
  int tid = threadIdx.x;          // 256 threads, 2 cols each
  int c = tid*2;
  int e0 = rp[row], e1 = rp[row+1];
  float a0=0.f, a1=0.f;
  for (int e=e0; e<e1; ++e){
    int s = ci[e];
    float ns = nsrc[s];
    h2f p = *(const h2f*)(h + (size_t)s*Wp + c);
    a0 += ns*(float)p[0];
    a1 += ns*(float)p[1];
  }
  float nd = ndst[row];
  a0 = actf(a0*nd, ACT); a1 = actf(a1*nd, ACT);
  h2f o;
  o[0] = (_Float16)(c   < W ? a0 : 0.f);
  o[1] = (_Float16)(c+1 < W ? a1 : 0.f);
  *(h2f*)(outh + (size_t)row*Wp + c) = o;
}

// ---------------- SpMM gather, width 10 ----------------
template<int ACT>
__global__ void k_spmm10(const float* __restrict__ h, const int* __restrict__ rp,
                         const int* __restrict__ ci, const float* __restrict__ nsrc,
                         const float* __restrict__ ndst, float* __restrict__ out, int n)
{
  int idx = blockIdx.x*blockDim.x + threadIdx.x;
  if (idx >= n*10) return;
  int row = idx/10, c = idx - row*10;
  int e0 = rp[row], e1 = rp[row+1];
  float acc = 0.f;
  for (int e=e0; e<e1; ++e){
    int s = ci[e];
    acc += nsrc[s]*h[(size_t)s*10 + c];
  }
  out[idx] = actf(acc*ndst[row], ACT);
}

// ---------------- decoder layer 1: weights in registers ----------------
__global__ __launch_bounds__(512) void k_broad_reg(
    const float* __restrict__ Z, const float* __restrict__ W, const float* __restrict__ bias,
    _Float16* __restrict__ out, int M, int Mp, int Cc, int Cp)
{
  int tid = threadIdx.x;
  float wr[4][10], bv[4];
  #pragma unroll
  for (int j=0;j<4;++j){
    int c = tid + j*512;
    bool v = c < Cc;
    bv[j] = v ? bias[c] : 0.f;
    #pragma unroll
    for (int q=0;q<10;++q) wr[j][q] = v ? W[(size_t)q*Cc + c] : 0.f;
  }
  for (int row = blockIdx.x; row < Mp; row += gridDim.x){
    float zr[10];
    bool rv = row < M;
    #pragma unroll
    for (int q=0;q<10;++q) zr[q] = rv ? Z[(size_t)row*10 + q] : 0.f;
    #pragma unroll
    for (int j=0;j<4;++j){
      int c = tid + j*512;
      float v = bv[j];
      #pragma unroll
      for (int q=0;q<10;++q) v += zr[q]*wr[j][q];
      v = fmaxf(v, 0.f);
      out[(size_t)row*Cp + c] = (_Float16)((rv && c < Cc) ? v : 0.f);
    }
  }
}

__global__ void k_softmax10(const float* __restrict__ h, float* __restrict__ out, int M){
  int row = blockIdx.x*blockDim.x + threadIdx.x;
  if (row >= M) return;
  float v[10]; float mx=-1e30f;
  #pragma unroll
  for (int j=0;j<10;++j){ v[j]=h[(size_t)row*10+j]; mx=fmaxf(mx,v[j]); }
  float s=0.f;
  #pragma unroll
  for (int j=0;j<10;++j){ v[j]=expf(v[j]-mx); s+=v[j]; }
  float inv=1.f/s;
  #pragma unroll
  for (int j=0;j<10;++j) out[(size_t)row*10+j]=v[j]*inv;
}

__global__ void k_q(const float* __restrict__ z, const float* __restrict__ cluster,
                    float* __restrict__ qout, float* __restrict__ colsum, int M)
{
  __shared__ float part[10];
  if (threadIdx.x < 10) part[threadIdx.x] = 0.f;
  __syncthreads();
  int row = blockIdx.x*blockDim.x + threadIdx.x;
  if (row < M){
    float zr[10];
    #pragma unroll
    for (int j=0;j<10;++j) zr[j] = z[(size_t)row*10+j];
    float qv[10]; float s=0.f;
    #pragma unroll
    for (int k=0;k<10;++k){
      float d2=0.f;
      #pragma unroll
      for (int j=0;j<10;++j){ float t = zr[j]-cluster[k*10+j]; d2 += t*t; }
      float qq = 1.f/(1.f+d2);
      qv[k]=qq; s+=qq;
    }
    float inv = 1.f/s;
    #pragma unroll
    for (int k=0;k<10;++k){
      float val = qv[k]*inv;
      qout[(size_t)row*10+k] = val;
      atomicAdd(&part[k], val);
    }
  }
  __syncthreads();
  if (threadIdx.x < 10) atomicAdd(&colsum[threadIdx.x], part[threadIdx.x]);
}

__global__ void k_p(const float* __restrict__ q, const float* __restrict__ colsum,
                    float* __restrict__ pout, int M){
  int row = blockIdx.x*blockDim.x + threadIdx.x;
  if (row >= M) return;
  float w[10]; float s=0.f;
  #pragma unroll
  for (int k=0;k<10;++k){ float qq=q[(size_t)row*10+k]; float ww=qq*qq/colsum[k]; w[k]=ww; s+=ww; }
  float inv=1.f/s;
  #pragma unroll
  for (int k=0;k<10;++k) pout[(size_t)row*10+k]=w[k]*inv;
}

extern "C" void kernel_launch(void* const* d_in, const int* in_sizes, int n_in,
                              void* d_out, int out_size, void* d_ws, size_t ws_size,
                              hipStream_t stream)
{
  const float* x   = (const float*)d_in[0];
  const float* ew1 = (const float*)d_in[1];  const float* eb1 = (const float*)d_in[2];
  const float* ew2 = (const float*)d_in[3];  const float* eb2 = (const float*)d_in[4];
  const float* ew3 = (const float*)d_in[5];  const float* eb3 = (const float*)d_in[6];
  const float* zw  = (const float*)d_in[7];  const float* zb  = (const float*)d_in[8];
  const float* dw1 = (const float*)d_in[9];  const float* db1 = (const float*)d_in[10];
  const float* dw2 = (const float*)d_in[11]; const float* db2 = (const float*)d_in[12];
  const float* dw3 = (const float*)d_in[13]; const float* db3 = (const float*)d_in[14];
  const float* xw  = (const float*)d_in[15]; const float* xb  = (const float*)d_in[16];
  const float* g1  = (const float*)d_in[17];
  const float* g2  = (const float*)d_in[18];
  const float* g3  = (const float*)d_in[19];
  const float* g4  = (const float*)d_in[20];
  const float* g5  = (const float*)d_in[21];
  const float* m1w = (const float*)d_in[22]; const float* m1b = (const float*)d_in[23];
  const float* m2w = (const float*)d_in[24]; const float* m2b = (const float*)d_in[25];
  const float* m3w = (const float*)d_in[26]; const float* m3b = (const float*)d_in[27];
  const float* mlw = (const float*)d_in[28]; const float* mlb = (const float*)d_in[29];
  const float* cluster = (const float*)d_in[30];
  const int* src = (const int*)d_in[31];
  const int* dst = (const int*)d_in[32];

  const int NI=2000, H1=500, H2=500, H3=2000;
  const int N = in_sizes[0] / NI;      // 20000
  const int E = in_sizes[31];          // 320000
  const int M_tot = E + N;
  const int Mp = ((N + 127)/128)*128;  // 20096

  float* out = (float*)d_out;
  float* out_xbar = out;
  float* out_q    = out + (size_t)N*NI;
  float* out_pred = out_q + (size_t)N*10;
  float* out_p    = out_pred + (size_t)N*10;

  // ---- workspace carve ----
  char* base = (char*)d_ws;
  size_t off = 0;
  auto AF = [&](size_t e)->float*{ float* r=(float*)(base+off); off += ((e*sizeof(float)+15)&~(size_t)15); return r; };
  auto AI = [&](size_t e)->int*  { int*   r=(int*)  (base+off); off += ((e*sizeof(int)  +15)&~(size_t)15); return r; };
  auto AH = [&](size_t e)->_Float16*{ _Float16* r=(_Float16*)(base+off); off += ((e*sizeof(_Float16)+15)&~(size_t)15); return r; };

  int* deg_out = AI(N); int* deg_in = AI(N);
  int* rp = AI(N+1); int* cursor = AI(N); int* ci = AI(M_tot);
  float* nsrc = AF(N); float* ndst = AF(N); float* colsum = AF(16);
  float* zlat = AF((size_t)N*10);
  float* pre4 = AF((size_t)N*10);
  float* z4   = AF((size_t)N*10);
  float* pre5 = AF((size_t)N*10);
  float* hbuf = AF((size_t)N*10);
  float* Ybuf = AF((size_t)Mp*64);
  float* gm3  = AF((size_t)N*2);
  // fp16 buffers
  _Float16* xh    = AH((size_t)Mp*2048);  // x_h -> z3_h -> dh1_h
  _Float16* tra3h = AH((size_t)Mp*2048);
  _Float16* tra1h = AH((size_t)Mp*512);
  _Float16* tra2h = AH((size_t)Mp*512);
  _Float16* z1h   = AH((size_t)Mp*512);
  _Float16* z2h   = AH((size_t)Mp*512);
  _Float16* Ph    = AH((size_t)Mp*512);   // pre1_h -> agg2_h -> agg3_h -> dh3_h
  _Float16* Qh    = AH((size_t)Mp*512);   // mix1_h -> mix2_h -> dh2_h
  _Float16* z4zh  = AH((size_t)Mp*64);
  _Float16* wch   = AH((size_t)128*3136);
  _Float16* ew1h = AH((size_t)512*2048);
  _Float16* ew2h = AH((size_t)512*512);
  _Float16* ew3h = AH((size_t)2048*512);
  _Float16* dw2h = AH((size_t)512*2048);
  _Float16* dw3h = AH((size_t)512*512);
  _Float16* xwh  = AH((size_t)2048*512);
  _Float16* g1h  = AH((size_t)512*2048);
  _Float16* g2h  = AH((size_t)512*512);
  _Float16* g3h  = AH((size_t)2048*512);
  (void)ws_size; (void)out_size; (void)n_in;

  dim3 b256(256);
  // ---- graph build ----
  k_init_deg<<<(N+255)/256, b256, 0, stream>>>(deg_out, deg_in, N);
  k_count<<<(E+255)/256, b256, 0, stream>>>(src, dst, deg_out, deg_in, E);
  k_scan<<<1, 1024, 0, stream>>>(deg_in, rp, N);
  k_zero_i<<<(N+255)/256, b256, 0, stream>>>(cursor, N);
  k_zero_f<<<1, 64, 0, stream>>>(colsum, 16);
  k_fill<<<(M_tot+255)/256, b256, 0, stream>>>(src, dst, rp, cursor, ci, E, N);
  k_norms<<<(N+255)/256, b256, 0, stream>>>(deg_out, deg_in, nsrc, ndst, N);

  // ---- conversions ----
  {
    long tot = (long)Mp*(2048/8);
    k_conv_a<<<(tot+255)/256, b256, 0, stream>>>(x, xh, N, NI, Mp, 2048);
  }
  #define CONVBT(W_, K_, N_, NP_, KP_, OUT_) \
    k_conv_bt<<<dim3((KP_)/32,(NP_)/32), b256, 0, stream>>>((W_), (OUT_), (K_), (N_), (NP_), (KP_))
  CONVBT(ew1, 2000, 500, 512, 2048, ew1h);
  CONVBT(ew2, 500, 500, 512, 512, ew2h);
  CONVBT(ew3, 500, 2000, 2048, 512, ew3h);
  CONVBT(dw2, 2000, 500, 512, 2048, dw2h);
  CONVBT(dw3, 500, 500, 512, 512, dw3h);
  CONVBT(xw,  500, 2000, 2048, 512, xwh);
  CONVBT(g1,  2000, 500, 512, 2048, g1h);
  CONVBT(g2,  500, 500, 512, 512, g2h);
  CONVBT(g3,  500, 2000, 2048, 512, g3h);
  #undef CONVBT
  k_build_wc<<<(128*3136+255)/256, b256, 0, stream>>>(mlw, g5, wch);

  const int MT = Mp/128;   // 157
  #define HGEMM(ACT,BIAS,F32O,F16O, A_,BT_,BIASP_,C_,CH_, NV_,NP_,KP_) \
    k_hgemm<ACT,BIAS,F32O,F16O><<<dim3((NP_)/128, MT), b256, 0, stream>>>( \
      (A_),(BT_),(BIASP_),(C_),(CH_), N, (NV_), (NP_), (KP_))

  // ---- encoder (fp16 activations only) ----
  HGEMM(1,true, false,true,  xh,    ew1h, eb1, (float*)nullptr, tra1h, 500, 512, 2048);   // tra1h
  HGEMM(1,true, false,true,  tra1h, ew2h, eb2, (float*)nullptr, tra2h, 500, 512, 512);    // tra2h
  HGEMM(1,true, false,true,  tra2h, ew3h, eb3, (float*)nullptr, tra3h, 2000, 2048, 512);  // tra3h
  k_skinny10_h<<<512, b256, 0, stream>>>(tra3h, 2048, zw, 2000, zb, zlat, N, 0);          // zlat

  // ---- GCN branch ----
  HGEMM(0,false,false,true,  xh,  g1h, nullptr, (float*)nullptr, Ph, 500, 512, 2048);     // pre1h
  k_spmm2<2><<<N, b256, 0, stream>>>(Ph, rp, ci, nsrc, ndst, z1h, H1, 512);               // z1h (leaky)
  k_gate_mix_hh<<<N, b256, 0, stream>>>(tra1h, z1h, m1w, m1b, Qh, H1, 512);               // mix1h
  k_spmm2<0><<<N, b256, 0, stream>>>(Qh, rp, ci, nsrc, ndst, Ph, H1, 512);                // agg2h
  HGEMM(2,false,false,true,  Ph, g2h, nullptr, (float*)nullptr, z2h, 500, 512, 512);      // z2h (leaky)
  k_gate_mix_hh<<<N, b256, 0, stream>>>(tra2h, z2h, m2w, m2b, Qh, H2, 512);               // mix2h
  k_spmm2<0><<<N, b256, 0, stream>>>(Qh, rp, ci, nsrc, ndst, Ph, H2, 512);                // agg3h
  HGEMM(2,false,false,true,  Ph, g3h, nullptr, (float*)nullptr, xh, 2000, 2048, 512);     // z3h (xh slot)
  k_gate_coef_h<<<N, b256, 0, stream>>>(tra3h, xh, m3w, m3b, gm3, H3, 2048);              // gm3
  k_skinny10_mix<<<512, b256, 0, stream>>>(tra3h, xh, 2048, gm3, g4, 2000, pre4, N);      // pre4
  k_spmm10<2><<<(N*10+255)/256, b256, 0, stream>>>(pre4, rp, ci, nsrc, ndst, z4, N);      // z4
  k_tail64<<<(N*64+255)/256, b256, 0, stream>>>(z4, zlat, z4zh, N);
  k_hgemm_up5<<<dim3(1, MT), b256, 0, stream>>>(z1h, z2h, xh, z4zh, wch, Ybuf, N);
  k_up5_fin<<<(N+255)/256, b256, 0, stream>>>(Ybuf, mlb, pre5, N);
  k_spmm10<0><<<(N*10+255)/256, b256, 0, stream>>>(pre5, rp, ci, nsrc, ndst, hbuf, N);
  k_softmax10<<<(N+255)/256, b256, 0, stream>>>(hbuf, out_pred, N);
  // ---- clustering head ----
  k_q<<<(N+255)/256, b256, 0, stream>>>(zlat, cluster, out_q, colsum, N);
  k_p<<<(N+255)/256, b256, 0, stream>>>(out_q, colsum, out_p, N);

  // ---- decoder (xh/z3h dead after up5 GEMM) ----
  k_broad_reg<<<512, 512, 0, stream>>>(zlat, dw1, db1, xh, N, Mp, H3, 2048);              // dh1h
  HGEMM(1,true, false,true,  xh, dw2h, db2, (float*)nullptr, Qh, 500, 512, 2048);         // dh2h
  HGEMM(1,true, false,true,  Qh, dw3h, db3, (float*)nullptr, Ph, 500, 512, 512);          // dh3h
  HGEMM(0,true, true, false, Ph, xwh,  xb,  out_xbar, (_Float16*)nullptr, 2000, 2048, 512); // x_bar
  #undef HGEMM
}

// Round 6
// 1672.901 us; speedup vs baseline: 1.4484x; 1.0527x over previous
//
#include <hip/hip_runtime.h>
#include <cstdint>

typedef _Float16 half8 __attribute__((ext_vector_type(8)));
typedef _Float16 h2f __attribute__((ext_vector_type(2)));
typedef float f32x4 __attribute__((ext_vector_type(4)));

__device__ __forceinline__ float leakyf(float v){ return v > 0.f ? v : 0.01f*v; }
__device__ __forceinline__ float actf(float v, int act){
  if (act == 1) return fmaxf(v, 0.f);
  if (act == 2) return leakyf(v);
  return v;
}
__device__ __forceinline__ unsigned pkh(float a, float b){
  h2f p; p[0]=(_Float16)a; p[1]=(_Float16)b; return __builtin_bit_cast(unsigned, p);
}
__device__ __forceinline__ h2f uph(unsigned u){ return __builtin_bit_cast(h2f, u); }

__device__ __forceinline__ void gl_lds16(const void* g, void* l){
  __builtin_amdgcn_global_load_lds((const __attribute__((address_space(1))) void*)g,
                                   (__attribute__((address_space(3))) void*)l, 16, 0, 0);
}

// ---------------- graph build ----------------
__global__ void k_init_deg(int* deg_out, int* deg_in, int n){
  int i = blockIdx.x*blockDim.x + threadIdx.x;
  if (i < n){ deg_out[i] = 1; deg_in[i] = 1; }
}
__global__ void k_count(const int* __restrict__ src, const int* __restrict__ dst,
                        int* deg_out, int* deg_in, int e){
  int i = blockIdx.x*blockDim.x + threadIdx.x;
  if (i < e){ atomicAdd(&deg_out[src[i]], 1); atomicAdd(&deg_in[dst[i]], 1); }
}
__global__ void k_scan(const int* __restrict__ deg, int* rp, int n){
  __shared__ int sums[1024];
  int t = threadIdx.x;
  int per = (n + 1023)/1024;
  int base = t*per;
  int s = 0;
  for (int i = 0; i < per; ++i){ int j = base+i; if (j < n) s += deg[j]; }
  sums[t] = s; __syncthreads();
  for (int off = 1; off < 1024; off <<= 1){
    int v = 0;
    if (t >= off) v = sums[t-off];
    __syncthreads();
    if (t >= off) sums[t] += v;
    __syncthreads();
  }
  int run = (t == 0) ? 0 : sums[t-1];
  for (int i = 0; i < per; ++i){ int j = base+i; if (j < n){ rp[j] = run; run += deg[j]; } }
  if (t == 1023) rp[n] = sums[1023];
}
__global__ void k_zero_i(int* p, int n){ int i=blockIdx.x*blockDim.x+threadIdx.x; if(i<n) p[i]=0; }
__global__ void k_zero_f(float* p, int n){ int i=blockIdx.x*blockDim.x+threadIdx.x; if(i<n) p[i]=0.f; }
__global__ void k_fill(const int* __restrict__ src, const int* __restrict__ dst,
                       const int* __restrict__ rp, int* cursor, int* ci, int e, int n){
  int i = blockIdx.x*blockDim.x + threadIdx.x;
  if (i >= e + n) return;
  int s, d;
  if (i < e){ s = src[i]; d = dst[i]; } else { s = d = i - e; }
  int pos = atomicAdd(&cursor[d], 1);
  ci[rp[d] + pos] = s;
}
__global__ void k_norms(const int* deg_out, const int* deg_in, float* nsrc, float* ndst, int n){
  int i = blockIdx.x*blockDim.x + threadIdx.x;
  if (i < n){ nsrc[i] = rsqrtf((float)deg_out[i]); ndst[i] = rsqrtf((float)deg_in[i]); }
}

// ---------------- conversions ----------------
__global__ void k_conv_a(const float* __restrict__ in, _Float16* __restrict__ out,
                         int M, int K, int Mp, int Kp){
  long idx = (long)blockIdx.x*blockDim.x + threadIdx.x;
  long total = (long)Mp*(Kp/8);
  if (idx >= total) return;
  int kp8 = Kp/8;
  int m = (int)(idx / kp8);
  int k8 = (int)(idx % kp8) * 8;
  half8 o;
  #pragma unroll
  for (int j=0;j<8;++j){
    int k = k8+j;
    o[j] = (_Float16)((m<M && k<K) ? in[(size_t)m*K + k] : 0.f);
  }
  *(half8*)&out[(size_t)m*Kp + k8] = o;
}
__global__ void k_conv_bt(const float* __restrict__ in, _Float16* __restrict__ out,
                          int K, int N, int Np, int Kp){
  __shared__ float t[32][33];
  int kb = blockIdx.x*32, nb = blockIdx.y*32;
  int tx = threadIdx.x & 31, ty = threadIdx.x >> 5;
  for (int r=ty; r<32; r+=8){
    int k = kb+r, n = nb+tx;
    t[r][tx] = (k<K && n<N) ? in[(size_t)k*N+n] : 0.f;
  }
  __syncthreads();
  for (int r=ty; r<32; r+=8){
    int n = nb+r, k = kb+tx;
    if (n<Np && k<Kp) out[(size_t)n*Kp+k] = (_Float16)t[tx][r];
  }
}

// build Wc [128 x 3136] fp16: packed mlw + block-diag g5 over padded segment layout
__global__ void k_build_wc(const float* __restrict__ mlw, const float* __restrict__ g5,
                           _Float16* __restrict__ wc){
  int idx = blockIdx.x*blockDim.x + threadIdx.x;
  if (idx >= 128*3136) return;
  int c = idx / 3136, k = idx - (idx/3136)*3136;
  int seg = -1, real_k = 0;
  if (k < 512){ if (k < 500){ seg=0; real_k=k; } }
  else if (k < 1024){ int kk=k-512; if (kk<500){ seg=1; real_k=500+kk; } }
  else if (k < 3072){ int kk=k-1024; if (kk<2000){ seg=2; real_k=1000+kk; } }
  else { int kk=k-3072; if (kk<10){ seg=3; real_k=3000+kk; } else if (kk<20){ seg=4; real_k=3010+kk-10; } }
  float val = 0.f;
  if (seg >= 0){
    if (c < 5) val = mlw[(size_t)real_k*5 + c];
    else if (c < 55){ int t=c-5; if (t/10 == seg) val = g5[(size_t)real_k*10 + (t-(t/10)*10)]; }
  }
  wc[(size_t)c*3136 + k] = (_Float16)val;
}

// ---------------- fp16 MFMA GEMM: Ch = act(A @ B^T + bias), fp16 out ----------------
template<int ACT, bool BIAS>
__global__ __launch_bounds__(256) void k_hgemm(
    const _Float16* __restrict__ A, const _Float16* __restrict__ BT,
    const float* __restrict__ bias, _Float16* __restrict__ Ch,
    int M, int Nvalid, long Np, long Kp, long lda)
{
  __shared__ __align__(16) _Float16 Asm[128*32];
  __shared__ __align__(16) _Float16 Bsm[128*32];
  const int m0 = blockIdx.y*128, n0 = blockIdx.x*128;
  const int tid = threadIdx.x;
  const int l = tid & 63, w = tid >> 6;
  const int wr = w >> 1, wc = w & 1;
  const int srow = tid >> 2, sseg = tid & 3;
  f32x4 acc[4][4] = {};

  for (long k0 = 0; k0 < Kp; k0 += 32){
    #pragma unroll
    for (int i=0;i<2;++i){
      int ar = i*64 + srow;
      gl_lds16(A  + (size_t)(m0+ar)*lda + k0 + sseg*8, (char*)Asm + i*4096 + (size_t)tid*16);
      gl_lds16(BT + (size_t)(n0+ar)*Kp + k0 + sseg*8, (char*)Bsm + i*4096 + (size_t)tid*16);
    }
    __syncthreads();
    half8 af[4], bf[4];
    #pragma unroll
    for (int mi=0;mi<4;++mi)
      af[mi] = *(const half8*)&Asm[(size_t)(wr*64 + mi*16 + (l&15))*32 + (l>>4)*8];
    #pragma unroll
    for (int nj=0;nj<4;++nj)
      bf[nj] = *(const half8*)&Bsm[(size_t)(wc*64 + nj*16 + (l&15))*32 + (l>>4)*8];
    #pragma unroll
    for (int mi=0;mi<4;++mi)
      #pragma unroll
      for (int nj=0;nj<4;++nj)
        acc[mi][nj] = __builtin_amdgcn_mfma_f32_16x16x32_f16(af[mi], bf[nj], acc[mi][nj], 0,0,0);
    __syncthreads();
  }

  const int cr = (l>>4)*4, cc = l&15;
  #pragma unroll
  for (int mi=0;mi<4;++mi){
    #pragma unroll
    for (int nj=0;nj<4;++nj){
      int cbase = n0 + wc*64 + nj*16 + cc;
      bool cvalid = cbase < Nvalid;
      #pragma unroll
      for (int q=0;q<4;++q){
        int r = m0 + wr*64 + mi*16 + cr + q;
        float v = acc[mi][nj][q];
        if (BIAS && cvalid) v += bias[cbase];
        if (ACT==1) v = fmaxf(v,0.f); else if (ACT==2) v = leakyf(v);
        if (!cvalid) v = 0.f;
        Ch[(size_t)r*Np + cbase] = (_Float16)(r < M ? v : 0.f);
      }
    }
  }
}

// ---------------- dual GEMM: cols 0-511 = relu(x@ew1+eb1), cols 512-1023 = x@g1 ----------------
__global__ __launch_bounds__(256) void k_hgemm_dual(
    const _Float16* __restrict__ A, const _Float16* __restrict__ BT,
    const float* __restrict__ eb1, _Float16* __restrict__ Ch, int M)
{
  const long Kp = 2048;
  __shared__ __align__(16) _Float16 Asm[128*32];
  __shared__ __align__(16) _Float16 Bsm[128*32];
  const int m0 = blockIdx.y*128, n0 = blockIdx.x*128;
  const int tid = threadIdx.x;
  const int l = tid & 63, w = tid >> 6;
  const int wr = w >> 1, wc = w & 1;
  const int srow = tid >> 2, sseg = tid & 3;
  f32x4 acc[4][4] = {};

  for (long k0 = 0; k0 < Kp; k0 += 32){
    #pragma unroll
    for (int i=0;i<2;++i){
      int ar = i*64 + srow;
      gl_lds16(A  + (size_t)(m0+ar)*Kp + k0 + sseg*8, (char*)Asm + i*4096 + (size_t)tid*16);
      gl_lds16(BT + (size_t)(n0+ar)*Kp + k0 + sseg*8, (char*)Bsm + i*4096 + (size_t)tid*16);
    }
    __syncthreads();
    half8 af[4], bf[4];
    #pragma unroll
    for (int mi=0;mi<4;++mi)
      af[mi] = *(const half8*)&Asm[(size_t)(wr*64 + mi*16 + (l&15))*32 + (l>>4)*8];
    #pragma unroll
    for (int nj=0;nj<4;++nj)
      bf[nj] = *(const half8*)&Bsm[(size_t)(wc*64 + nj*16 + (l&15))*32 + (l>>4)*8];
    #pragma unroll
    for (int mi=0;mi<4;++mi)
      #pragma unroll
      for (int nj=0;nj<4;++nj)
        acc[mi][nj] = __builtin_amdgcn_mfma_f32_16x16x32_f16(af[mi], bf[nj], acc[mi][nj], 0,0,0);
    __syncthreads();
  }

  const int cr = (l>>4)*4, cc = l&15;
  #pragma unroll
  for (int mi=0;mi<4;++mi){
    #pragma unroll
    for (int nj=0;nj<4;++nj){
      int cbase = n0 + wc*64 + nj*16 + cc;
      bool hi = cbase >= 512;
      int cl = hi ? cbase - 512 : cbase;
      bool cvalid = cl < 500;
      #pragma unroll
      for (int q=0;q<4;++q){
        int r = m0 + wr*64 + mi*16 + cr + q;
        float v = acc[mi][nj][q];
        if (!hi && cvalid){ v += eb1[cl]; v = fmaxf(v, 0.f); }
        if (!cvalid) v = 0.f;
        Ch[(size_t)r*1024 + cbase] = (_Float16)(r < M ? v : 0.f);
      }
    }
  }
}

// ---------------- f32-out GEMM with LDS-transposed coalesced epilogue (x_bar) ----------------
__global__ __launch_bounds__(256) void k_hgemm_f32t(
    const _Float16* __restrict__ A, const _Float16* __restrict__ BT,
    const float* __restrict__ bias, float* __restrict__ C,
    int M, int Nvalid, long Kp, long lda)
{
  __shared__ __align__(16) _Float16 Asm[128*32];
  __shared__ __align__(16) _Float16 Bsm[128*32];
  __shared__ __align__(16) float scr[16*128];
  const int m0 = blockIdx.y*128, n0 = blockIdx.x*128;
  const int tid = threadIdx.x;
  const int l = tid & 63, w = tid >> 6;
  const int wr = w >> 1, wc = w & 1;
  const int srow = tid >> 2, sseg = tid & 3;
  f32x4 acc[4][4] = {};

  for (long k0 = 0; k0 < Kp; k0 += 32){
    #pragma unroll
    for (int i=0;i<2;++i){
      int ar = i*64 + srow;
      gl_lds16(A  + (size_t)(m0+ar)*lda + k0 + sseg*8, (char*)Asm + i*4096 + (size_t)tid*16);
      gl_lds16(BT + (size_t)(n0+ar)*Kp + k0 + sseg*8, (char*)Bsm + i*4096 + (size_t)tid*16);
    }
    __syncthreads();
    half8 af[4], bf[4];
    #pragma unroll
    for (int mi=0;mi<4;++mi)
      af[mi] = *(const half8*)&Asm[(size_t)(wr*64 + mi*16 + (l&15))*32 + (l>>4)*8];
    #pragma unroll
    for (int nj=0;nj<4;++nj)
      bf[nj] = *(const half8*)&Bsm[(size_t)(wc*64 + nj*16 + (l&15))*32 + (l>>4)*8];
    #pragma unroll
    for (int mi=0;mi<4;++mi)
      #pragma unroll
      for (int nj=0;nj<4;++nj)
        acc[mi][nj] = __builtin_amdgcn_mfma_f32_16x16x32_f16(af[mi], bf[nj], acc[mi][nj], 0,0,0);
    __syncthreads();
  }

  const int cr = (l>>4)*4, cc = l&15;
  for (int p = 0; p < 8; ++p){        // 16-row slabs: rows m0 + p*16 ..
    if (wr == (p>>2)){
      int mi = p & 3;
      #pragma unroll
      for (int nj=0;nj<4;++nj){
        int cb = wc*64 + nj*16 + cc;
        float bv = (n0+cb < Nvalid) ? bias[n0+cb] : 0.f;
        #pragma unroll
        for (int q=0;q<4;++q)
          scr[(cr+q)*128 + cb] = acc[mi][nj][q] + bv;
      }
    }
    __syncthreads();
    #pragma unroll
    for (int j=0;j<2;++j){
      int flat = (tid + j*256)*4;
      int rl = flat >> 7, col = flat & 127;
      int r = m0 + p*16 + rl;
      int cb = n0 + col;
      if (r < M && cb < Nvalid)       // Nvalid % 4 == 0, no straddle
        *(f32x4*)&C[(size_t)r*Nvalid + cb] = *(const f32x4*)&scr[flat];
    }
    __syncthreads();
  }
}

// ---------------- up5 GEMM: Y[Mp x 64] = segA @ Wc^T (segmented A) ----------------
__global__ __launch_bounds__(256) void k_hgemm_up5(
    const _Float16* __restrict__ z1h, const _Float16* __restrict__ z2h,
    const _Float16* __restrict__ z3h, const _Float16* __restrict__ z4zh,
    const _Float16* __restrict__ Wc, float* __restrict__ Y, int M)
{
  __shared__ __align__(16) _Float16 Asm[128*32];
  __shared__ __align__(16) _Float16 Bsm[128*32];
  const int m0 = blockIdx.y*128;
  const int tid = threadIdx.x;
  const int l = tid & 63, w = tid >> 6;
  const int wr = w >> 1, wc = w & 1;
  const int srow = tid >> 2, sseg = tid & 3;
  f32x4 acc[4][4] = {};

  for (int k0 = 0; k0 < 3136; k0 += 32){
    const _Float16* ab; long astr; int kk;
    if (k0 < 512){ ab=z1h; astr=512; kk=k0; }
    else if (k0 < 1024){ ab=z2h; astr=512; kk=k0-512; }
    else if (k0 < 3072){ ab=z3h; astr=2048; kk=k0-1024; }
    else { ab=z4zh; astr=64; kk=k0-3072; }
    #pragma unroll
    for (int i=0;i<2;++i){
      int ar = i*64 + srow;
      gl_lds16(ab + (size_t)(m0+ar)*astr + kk + sseg*8, (char*)Asm + i*4096 + (size_t)tid*16);
      gl_lds16(Wc + (size_t)ar*3136 + k0 + sseg*8, (char*)Bsm + i*4096 + (size_t)tid*16);
    }
    __syncthreads();
    half8 af[4], bf[4];
    #pragma unroll
    for (int mi=0;mi<4;++mi)
      af[mi] = *(const half8*)&Asm[(size_t)(wr*64 + mi*16 + (l&15))*32 + (l>>4)*8];
    #pragma unroll
    for (int nj=0;nj<4;++nj)
      bf[nj] = *(const half8*)&Bsm[(size_t)(wc*64 + nj*16 + (l&15))*32 + (l>>4)*8];
    #pragma unroll
    for (int mi=0;mi<4;++mi)
      #pragma unroll
      for (int nj=0;nj<4;++nj)
        acc[mi][nj] = __builtin_amdgcn_mfma_f32_16x16x32_f16(af[mi], bf[nj], acc[mi][nj], 0,0,0);
    __syncthreads();
  }

  const int cr = (l>>4)*4, cc = l&15;
  #pragma unroll
  for (int mi=0;mi<4;++mi){
    #pragma unroll
    for (int nj=0;nj<4;++nj){
      int cbase = wc*64 + nj*16 + cc;
      if (cbase >= 64) continue;
      #pragma unroll
      for (int q=0;q<4;++q){
        int r = m0 + wr*64 + mi*16 + cr + q;
        if (r < M) Y[(size_t)r*64 + cbase] = acc[mi][nj][q];
      }
    }
  }
}

// epilogue: u = l2(softmax(leaky(logits+mlb))); pre5 = sum_i u_i * P_i
__global__ void k_up5_fin(const float* __restrict__ Y, const float* __restrict__ mlb,
                          float* __restrict__ pre5, int M){
  int row = blockIdx.x*blockDim.x + threadIdx.x;
  if (row >= M) return;
  const float* y = Y + (size_t)row*64;
  float v[5]; float mx = -1e30f;
  #pragma unroll
  for (int c=0;c<5;++c){ float t = leakyf(y[c] + mlb[c]); v[c]=t; mx=fmaxf(mx,t); }
  float ss=0.f;
  #pragma unroll
  for (int c=0;c<5;++c){ v[c]=expf(v[c]-mx); ss += v[c]*v[c]; }
  float inv = rsqrtf(fmaxf(ss,1e-30f));
  #pragma unroll
  for (int c=0;c<5;++c) v[c] *= inv;
  #pragma unroll
  for (int c=0;c<10;++c){
    float s = 0.f;
    #pragma unroll
    for (int i=0;i<5;++i) s += v[i]*y[5 + 10*i + c];
    pre5[(size_t)row*10 + c] = s;
  }
}

// tail: z4zh[row][0:10]=z4, [10:20]=zlat, rest 0
__global__ void k_tail64(const float* __restrict__ z4, const float* __restrict__ zlat,
                         _Float16* __restrict__ z4zh, int M){
  int idx = blockIdx.x*blockDim.x + threadIdx.x;
  if (idx >= M*64) return;
  int row = idx >> 6, j = idx & 63;
  float v = 0.f;
  if (j < 10) v = z4[(size_t)row*10 + j];
  else if (j < 20) v = zlat[(size_t)row*10 + j - 10];
  z4zh[idx] = (_Float16)v;
}

// ---------------- skinny 10-out GEMM, fp16 A, LDS-staged transposed f32 weights ----------------
__global__ __launch_bounds__(256) void k_skinny10_h(
    const _Float16* __restrict__ A, long lda, const float* __restrict__ W, int K,
    const float* __restrict__ bias, float* __restrict__ out, int M, int act)
{
  __shared__ float wl[10*2000];
  int tid = threadIdx.x;
  for (int idx = tid; idx < K*10; idx += 256){
    int k = idx/10, c = idx - k*10;
    wl[c*K + k] = W[idx];
  }
  __syncthreads();
  int wv = tid >> 6, lane = tid & 63;
  int stride = gridDim.x*4;
  for (int row = blockIdx.x*4 + wv; row < M; row += stride){
    const _Float16* a = A + (size_t)row*lda;
    float acc[10];
    #pragma unroll
    for (int c=0;c<10;++c) acc[c]=0.f;
    for (int k0 = lane*2; k0 < K; k0 += 128){
      h2f t2 = *(const h2f*)(a + k0);
      float v0 = (float)t2[0], v1 = (float)t2[1];
      #pragma unroll
      for (int c=0;c<10;++c) acc[c] += v0*wl[c*K + k0] + v1*wl[c*K + k0 + 1];
    }
    #pragma unroll
    for (int c=0;c<10;++c){
      #pragma unroll
      for (int off=32; off; off>>=1) acc[c] += __shfl_down(acc[c], off);
    }
    if (lane == 0){
      #pragma unroll
      for (int c=0;c<10;++c){
        float v = acc[c] + (bias ? bias[c] : 0.f);
        out[(size_t)row*10 + c] = actf(v, act);
      }
    }
  }
}

// ---------------- fused gate3 + mix3@g4 (linearity: pre4 = mz*(z3@g4) + mt*(tra3@g4)) ----------------
__global__ __launch_bounds__(256) void k_fused3(
    const _Float16* __restrict__ tra, const _Float16* __restrict__ zin,
    const float* __restrict__ m3w, const float* __restrict__ b3,
    const float* __restrict__ g4, float* __restrict__ pre4, int M)
{
  const int K = 2000;
  __shared__ unsigned g4l[5*2000];   // fp16x2 col-pairs: 40 KB
  __shared__ unsigned mt01[2000];    // m3w tra rows, 8 KB
  __shared__ unsigned mz01[2000];    // m3w z rows, 8 KB
  int tid = threadIdx.x;
  for (int k = tid; k < K; k += 256){
    mt01[k] = pkh(m3w[2*k],       m3w[2*k+1]);
    mz01[k] = pkh(m3w[2*(K+k)],   m3w[2*(K+k)+1]);
  }
  for (int idx = tid; idx < K*5; idx += 256){
    int jp = idx / K, k = idx - jp*K;
    g4l[idx] = pkh(g4[(size_t)k*10 + 2*jp], g4[(size_t)k*10 + 2*jp + 1]);
  }
  __syncthreads();
  int wv = tid >> 6, lane = tid & 63;
  int stride = gridDim.x*4;
  for (int row = blockIdx.x*4 + wv; row < M; row += stride){
    const _Float16* tr = tra + (size_t)row*2048;
    const _Float16* zr = zin + (size_t)row*2048;
    float a0=0.f, a1=0.f;
    float t4[10], z4a[10];
    #pragma unroll
    for (int c=0;c<10;++c){ t4[c]=0.f; z4a[c]=0.f; }
    for (int k0 = lane*2; k0 < K; k0 += 128){
      h2f t2 = *(const h2f*)(tr + k0);
      h2f z2 = *(const h2f*)(zr + k0);
      #pragma unroll
      for (int j=0;j<2;++j){
        int k = k0 + j;
        float t = (float)t2[j], z = (float)z2[j];
        h2f mt = uph(mt01[k]); h2f mz = uph(mz01[k]);
        a0 += t*(float)mt[0] + z*(float)mz[0];
        a1 += t*(float)mt[1] + z*(float)mz[1];
        #pragma unroll
        for (int jp=0;jp<5;++jp){
          h2f p = uph(g4l[jp*K + k]);
          float p0 = (float)p[0], p1 = (float)p[1];
          t4[2*jp]   += t*p0;  t4[2*jp+1]  += t*p1;
          z4a[2*jp]  += z*p0;  z4a[2*jp+1] += z*p1;
        }
      }
    }
    #pragma unroll
    for (int off=32; off; off>>=1){
      a0 += __shfl_down(a0,off); a1 += __shfl_down(a1,off);
      #pragma unroll
      for (int c=0;c<10;++c){
        t4[c]  += __shfl_down(t4[c], off);
        z4a[c] += __shfl_down(z4a[c], off);
      }
    }
    if (lane == 0){
      float s0 = leakyf(a0 + b3[0]);
      float s1 = leakyf(a1 + b3[1]);
      float mx = fmaxf(s0, s1);
      float e0 = expf(s0-mx), e1 = expf(s1-mx);
      float inv = rsqrtf(fmaxf(e0*e0 + e1*e1, 1e-30f));
      float mzc = e0*inv, mtc = e1*inv;
      #pragma unroll
      for (int c=0;c<10;++c)
        pre4[(size_t)row*10 + c] = mzc*z4a[c] + mtc*t4[c];
    }
  }
}

// ---------------- fused gate+mix, fp16 in/out ----------------
__global__ void k_gate_mix_hh(const _Float16* __restrict__ tra, long Wpa,
                              const _Float16* __restrict__ zin, long Wpz,
                              const float* __restrict__ w, const float* __restrict__ b,
                              _Float16* __restrict__ mix, int W, long Wpo)
{
  int row = blockIdx.x;
  int tid = threadIdx.x;
  const _Float16* tr = tra + (size_t)row*Wpa;
  const _Float16* zr = zin + (size_t)row*Wpz;
  int c = tid*2;
  h2f t2 = *(const h2f*)(tr + c);
  h2f z2 = *(const h2f*)(zr + c);
  float a0=0.f, a1=0.f;
  #pragma unroll
  for (int j=0;j<2;++j){
    int k = c + j;
    if (k < W){
      float t = (float)t2[j], zv = (float)z2[j];
      a0 += t*w[2*k]   + zv*w[2*(W+k)];
      a1 += t*w[2*k+1] + zv*w[2*(W+k)+1];
    }
  }
  #pragma unroll
  for (int off=32; off; off>>=1){ a0 += __shfl_down(a0,off); a1 += __shfl_down(a1,off); }
  __shared__ float red0[4], red1[4], m01[2];
  int wv = tid>>6, ln = tid&63;
  if (ln==0){ red0[wv]=a0; red1[wv]=a1; }
  __syncthreads();
  if (tid==0){
    float s0 = red0[0]+red0[1]+red0[2]+red0[3] + b[0];
    float s1 = red1[0]+red1[1]+red1[2]+red1[3] + b[1];
    s0 = leakyf(s0); s1 = leakyf(s1);
    float mx = fmaxf(s0,s1);
    float e0 = expf(s0-mx), e1 = expf(s1-mx);
    float inv = rsqrtf(fmaxf(e0*e0+e1*e1, 1e-30f));
    m01[0] = e0*inv; m01[1] = e1*inv;
  }
  __syncthreads();
  float mz = m01[0], mt = m01[1];
  h2f o;
  #pragma unroll
  for (int j=0;j<2;++j){
    int k = c + j;
    o[j] = (_Float16)(k < W ? (mz*(float)z2[j] + mt*(float)t2[j]) : 0.f);
  }
  *(h2f*)(mix + (size_t)row*Wpo + c) = o;
}

// ---------------- SpMM gather, fp16x2 loads; fp16 out ----------------
template<int ACT>
__global__ void k_spmm2(const _Float16* __restrict__ h, long Wpi, const int* __restrict__ rp,
                        const int* __restrict__ ci, const float* __restrict__ nsrc,
                        const float* __restrict__ ndst, _Float16* __restrict__ outh,
                        int W, long Wpo)
{
  int row = blockIdx.x;
  int tid = threadIdx.x;          // 256 threads, 2 cols each
  int c = tid*2;
  int e0 = rp[row], e1 = rp[row+1];
  float a0=0.f, a1=0.f;
  for (int e=e0; e<e1; ++e){
    int s = ci[e];
    float ns = nsrc[s];
    h2f p = *(const h2f*)(h + (size_t)s*Wpi + c);
    a0 += ns*(float)p[0];
    a1 += ns*(float)p[1];
  }
  float nd = ndst[row];
  a0 = actf(a0*nd, ACT); a1 = actf(a1*nd, ACT);
  h2f o;
  o[0] = (_Float16)(c   < W ? a0 : 0.f);
  o[1] = (_Float16)(c+1 < W ? a1 : 0.f);
  *(h2f*)(outh + (size_t)row*Wpo + c) = o;
}

// ---------------- SpMM gather, width 10 ----------------
template<int ACT>
__global__ void k_spmm10(const float* __restrict__ h, const int* __restrict__ rp,
                         const int* __restrict__ ci, const float* __restrict__ nsrc,
                         const float* __restrict__ ndst, float* __restrict__ out, int n)
{
  int idx = blockIdx.x*blockDim.x + threadIdx.x;
  if (idx >= n*10) return;
  int row = idx/10, c = idx - row*10;
  int e0 = rp[row], e1 = rp[row+1];
  float acc = 0.f;
  for (int e=e0; e<e1; ++e){
    int s = ci[e];
    acc += nsrc[s]*h[(size_t)s*10 + c];
  }
  out[idx] = actf(acc*ndst[row], ACT);
}

// ---------------- decoder layer 1: weights in registers ----------------
__global__ __launch_bounds__(512) void k_broad_reg(
    const float* __restrict__ Z, const float* __restrict__ W, const float* __restrict__ bias,
    _Float16* __restrict__ out, int M, int Mp, int Cc, int Cp)
{
  int tid = threadIdx.x;
  float wr[4][10], bv[4];
  #pragma unroll
  for (int j=0;j<4;++j){
    int c = tid + j*512;
    bool v = c < Cc;
    bv[j] = v ? bias[c] : 0.f;
    #pragma unroll
    for (int q=0;q<10;++q) wr[j][q] = v ? W[(size_t)q*Cc + c] : 0.f;
  }
  for (int row = blockIdx.x; row < Mp; row += gridDim.x){
    float zr[10];
    bool rv = row < M;
    #pragma unroll
    for (int q=0;q<10;++q) zr[q] = rv ? Z[(size_t)row*10 + q] : 0.f;
    #pragma unroll
    for (int j=0;j<4;++j){
      int c = tid + j*512;
      float v = bv[j];
      #pragma unroll
      for (int q=0;q<10;++q) v += zr[q]*wr[j][q];
      v = fmaxf(v, 0.f);
      out[(size_t)row*Cp + c] = (_Float16)((rv && c < Cc) ? v : 0.f);
    }
  }
}

__global__ void k_softmax10(const float* __restrict__ h, float* __restrict__ out, int M){
  int row = blockIdx.x*blockDim.x + threadIdx.x;
  if (row >= M) return;
  float v[10]; float mx=-1e30f;
  #pragma unroll
  for (int j=0;j<10;++j){ v[j]=h[(size_t)row*10+j]; mx=fmaxf(mx,v[j]); }
  float s=0.f;
  #pragma unroll
  for (int j=0;j<10;++j){ v[j]=expf(v[j]-mx); s+=v[j]; }
  float inv=1.f/s;
  #pragma unroll
  for (int j=0;j<10;++j) out[(size_t)row*10+j]=v[j]*inv;
}

__global__ void k_q(const float* __restrict__ z, const float* __restrict__ cluster,
                    float* __restrict__ qout, float* __restrict__ colsum, int M)
{
  __shared__ float part[10];
  if (threadIdx.x < 10) part[threadIdx.x] = 0.f;
  __syncthreads();
  int row = blockIdx.x*blockDim.x + threadIdx.x;
  if (row < M){
    float zr[10];
    #pragma unroll
    for (int j=0;j<10;++j) zr[j] = z[(size_t)row*10+j];
    float qv[10]; float s=0.f;
    #pragma unroll
    for (int k=0;k<10;++k){
      float d2=0.f;
      #pragma unroll
      for (int j=0;j<10;++j){ float t = zr[j]-cluster[k*10+j]; d2 += t*t; }
      float qq = 1.f/(1.f+d2);
      qv[k]=qq; s+=qq;
    }
    float inv = 1.f/s;
    #pragma unroll
    for (int k=0;k<10;++k){
      float val = qv[k]*inv;
      qout[(size_t)row*10+k] = val;
      atomicAdd(&part[k], val);
    }
  }
  __syncthreads();
  if (threadIdx.x < 10) atomicAdd(&colsum[threadIdx.x], part[threadIdx.x]);
}

__global__ void k_p(const float* __restrict__ q, const float* __restrict__ colsum,
                    float* __restrict__ pout, int M){
  int row = blockIdx.x*blockDim.x + threadIdx.x;
  if (row >= M) return;
  float w[10]; float s=0.f;
  #pragma unroll
  for (int k=0;k<10;++k){ float qq=q[(size_t)row*10+k]; float ww=qq*qq/colsum[k]; w[k]=ww; s+=ww; }
  float inv=1.f/s;
  #pragma unroll
  for (int k=0;k<10;++k) pout[(size_t)row*10+k]=w[k]*inv;
}

extern "C" void kernel_launch(void* const* d_in, const int* in_sizes, int n_in,
                              void* d_out, int out_size, void* d_ws, size_t ws_size,
                              hipStream_t stream)
{
  const float* x   = (const float*)d_in[0];
  const float* ew1 = (const float*)d_in[1];  const float* eb1 = (const float*)d_in[2];
  const float* ew2 = (const float*)d_in[3];  const float* eb2 = (const float*)d_in[4];
  const float* ew3 = (const float*)d_in[5];  const float* eb3 = (const float*)d_in[6];
  const float* zw  = (const float*)d_in[7];  const float* zb  = (const float*)d_in[8];
  const float* dw1 = (const float*)d_in[9];  const float* db1 = (const float*)d_in[10];
  const float* dw2 = (const float*)d_in[11]; const float* db2 = (const float*)d_in[12];
  const float* dw3 = (const float*)d_in[13]; const float* db3 = (const float*)d_in[14];
  const float* xw  = (const float*)d_in[15]; const float* xb  = (const float*)d_in[16];
  const float* g1  = (const float*)d_in[17];
  const float* g2  = (const float*)d_in[18];
  const float* g3  = (const float*)d_in[19];
  const float* g4  = (const float*)d_in[20];
  const float* g5  = (const float*)d_in[21];
  const float* m1w = (const float*)d_in[22]; const float* m1b = (const float*)d_in[23];
  const float* m2w = (const float*)d_in[24]; const float* m2b = (const float*)d_in[25];
  const float* m3w = (const float*)d_in[26]; const float* m3b = (const float*)d_in[27];
  const float* mlw = (const float*)d_in[28]; const float* mlb = (const float*)d_in[29];
  const float* cluster = (const float*)d_in[30];
  const int* src = (const int*)d_in[31];
  const int* dst = (const int*)d_in[32];

  const int NI=2000, H1=500, H2=500, H3=2000;
  const int N = in_sizes[0] / NI;      // 20000
  const int E = in_sizes[31];          // 320000
  const int M_tot = E + N;
  const int Mp = ((N + 127)/128)*128;  // 20096

  float* out = (float*)d_out;
  float* out_xbar = out;
  float* out_q    = out + (size_t)N*NI;
  float* out_pred = out_q + (size_t)N*10;
  float* out_p    = out_pred + (size_t)N*10;

  // ---- workspace carve ----
  char* base = (char*)d_ws;
  size_t off = 0;
  auto AF = [&](size_t e)->float*{ float* r=(float*)(base+off); off += ((e*sizeof(float)+15)&~(size_t)15); return r; };
  auto AI = [&](size_t e)->int*  { int*   r=(int*)  (base+off); off += ((e*sizeof(int)  +15)&~(size_t)15); return r; };
  auto AH = [&](size_t e)->_Float16*{ _Float16* r=(_Float16*)(base+off); off += ((e*sizeof(_Float16)+15)&~(size_t)15); return r; };

  int* deg_out = AI(N); int* deg_in = AI(N);
  int* rp = AI(N+1); int* cursor = AI(N); int* ci = AI(M_tot);
  float* nsrc = AF(N); float* ndst = AF(N); float* colsum = AF(16);
  float* zlat = AF((size_t)N*10);
  float* pre4 = AF((size_t)N*10);
  float* z4   = AF((size_t)N*10);
  float* pre5 = AF((size_t)N*10);
  float* hbuf = AF((size_t)N*10);
  float* Ybuf = AF((size_t)Mp*64);
  // fp16 buffers
  _Float16* xh    = AH((size_t)Mp*2048);   // x_h -> z3_h -> dh1_h
  _Float16* tra3h = AH((size_t)Mp*2048);
  _Float16* dualh = AH((size_t)Mp*1024);   // cols 0-511 tra1h | cols 512-1023 pre1h
  _Float16* tra2h = AH((size_t)Mp*512);
  _Float16* z1h   = AH((size_t)Mp*512);
  _Float16* z2h   = AH((size_t)Mp*512);
  _Float16* Ph    = AH((size_t)Mp*512);    // agg2_h -> agg3_h -> dh3_h
  _Float16* Qh    = AH((size_t)Mp*512);    // mix1_h -> mix2_h -> dh2_h
  _Float16* z4zh  = AH((size_t)Mp*64);
  _Float16* wch   = AH((size_t)128*3136);
  _Float16* ewg1h = AH((size_t)1024*2048); // rows 0-511 ew1^T | rows 512-1023 g1^T
  _Float16* ew1h  = ewg1h;
  _Float16* g1h   = ewg1h + (size_t)512*2048;
  _Float16* ew2h = AH((size_t)512*512);
  _Float16* ew3h = AH((size_t)2048*512);
  _Float16* dw2h = AH((size_t)512*2048);
  _Float16* dw3h = AH((size_t)512*512);
  _Float16* xwh  = AH((size_t)2048*512);
  _Float16* g2h  = AH((size_t)512*512);
  _Float16* g3h  = AH((size_t)2048*512);
  (void)ws_size; (void)out_size; (void)n_in;

  dim3 b256(256);
  // ---- graph build ----
  k_init_deg<<<(N+255)/256, b256, 0, stream>>>(deg_out, deg_in, N);
  k_count<<<(E+255)/256, b256, 0, stream>>>(src, dst, deg_out, deg_in, E);
  k_scan<<<1, 1024, 0, stream>>>(deg_in, rp, N);
  k_zero_i<<<(N+255)/256, b256, 0, stream>>>(cursor, N);
  k_zero_f<<<1, 64, 0, stream>>>(colsum, 16);
  k_fill<<<(M_tot+255)/256, b256, 0, stream>>>(src, dst, rp, cursor, ci, E, N);
  k_norms<<<(N+255)/256, b256, 0, stream>>>(deg_out, deg_in, nsrc, ndst, N);

  // ---- conversions ----
  {
    long tot = (long)Mp*(2048/8);
    k_conv_a<<<(tot+255)/256, b256, 0, stream>>>(x, xh, N, NI, Mp, 2048);
  }
  #define CONVBT(W_, K_, N_, NP_, KP_, OUT_) \
    k_conv_bt<<<dim3((KP_)/32,(NP_)/32), b256, 0, stream>>>((W_), (OUT_), (K_), (N_), (NP_), (KP_))
  CONVBT(ew1, 2000, 500, 512, 2048, ew1h);
  CONVBT(g1,  2000, 500, 512, 2048, g1h);
  CONVBT(ew2, 500, 500, 512, 512, ew2h);
  CONVBT(ew3, 500, 2000, 2048, 512, ew3h);
  CONVBT(dw2, 2000, 500, 512, 2048, dw2h);
  CONVBT(dw3, 500, 500, 512, 512, dw3h);
  CONVBT(xw,  500, 2000, 2048, 512, xwh);
  CONVBT(g2,  500, 500, 512, 512, g2h);
  CONVBT(g3,  500, 2000, 2048, 512, g3h);
  #undef CONVBT
  k_build_wc<<<(128*3136+255)/256, b256, 0, stream>>>(mlw, g5, wch);

  const int MT = Mp/128;   // 157
  #define HGEMM(ACT,BIAS, A_,BT_,BIASP_,CH_, NV_,NP_,KP_,LDA_) \
    k_hgemm<ACT,BIAS><<<dim3((NP_)/128, MT), b256, 0, stream>>>( \
      (A_),(BT_),(BIASP_),(CH_), N, (NV_), (NP_), (KP_), (LDA_))

  // ---- encoder + first GCN layer fused on the x pass ----
  k_hgemm_dual<<<dim3(8, MT), b256, 0, stream>>>(xh, ewg1h, eb1, dualh, N);                // tra1h|pre1h
  HGEMM(1,true,  dualh, ew2h, eb2, tra2h, 500, 512, 512, 1024);                            // tra2h
  HGEMM(1,true,  tra2h, ew3h, eb3, tra3h, 2000, 2048, 512, 512);                           // tra3h
  k_skinny10_h<<<512, b256, 0, stream>>>(tra3h, 2048, zw, 2000, zb, zlat, N, 0);           // zlat

  // ---- GCN branch ----
  k_spmm2<2><<<N, b256, 0, stream>>>(dualh+512, 1024, rp, ci, nsrc, ndst, z1h, H1, 512);   // z1h (leaky)
  k_gate_mix_hh<<<N, b256, 0, stream>>>(dualh, 1024, z1h, 512, m1w, m1b, Qh, H1, 512);     // mix1h
  k_spmm2<0><<<N, b256, 0, stream>>>(Qh, 512, rp, ci, nsrc, ndst, Ph, H1, 512);            // agg2h
  HGEMM(2,false, Ph, g2h, nullptr, z2h, 500, 512, 512, 512);                               // z2h (leaky)
  k_gate_mix_hh<<<N, b256, 0, stream>>>(tra2h, 512, z2h, 512, m2w, m2b, Qh, H2, 512);      // mix2h
  k_spmm2<0><<<N, b256, 0, stream>>>(Qh, 512, rp, ci, nsrc, ndst, Ph, H2, 512);            // agg3h
  HGEMM(2,false, Ph, g3h, nullptr, xh, 2000, 2048, 512, 512);                              // z3h (xh slot)
  k_fused3<<<512, b256, 0, stream>>>(tra3h, xh, m3w, m3b, g4, pre4, N);                    // gate3 + mix@g4
  k_spmm10<2><<<(N*10+255)/256, b256, 0, stream>>>(pre4, rp, ci, nsrc, ndst, z4, N);       // z4
  k_tail64<<<(N*64+255)/256, b256, 0, stream>>>(z4, zlat, z4zh, N);
  k_hgemm_up5<<<dim3(1, MT), b256, 0, stream>>>(z1h, z2h, xh, z4zh, wch, Ybuf, N);
  k_up5_fin<<<(N+255)/256, b256, 0, stream>>>(Ybuf, mlb, pre5, N);
  k_spmm10<0><<<(N*10+255)/256, b256, 0, stream>>>(pre5, rp, ci, nsrc, ndst, hbuf, N);
  k_softmax10<<<(N+255)/256, b256, 0, stream>>>(hbuf, out_pred, N);
  // ---- clustering head ----
  k_q<<<(N+255)/256, b256, 0, stream>>>(zlat, cluster, out_q, colsum, N);
  k_p<<<(N+255)/256, b256, 0, stream>>>(out_q, colsum, out_p, N);

  // ---- decoder (xh/z3h dead after up5 GEMM) ----
  k_broad_reg<<<512, 512, 0, stream>>>(zlat, dw1, db1, xh, N, Mp, H3, 2048);               // dh1h
  HGEMM(1,true,  xh, dw2h, db2, Qh, 500, 512, 2048, 2048);                                 // dh2h
  HGEMM(1,true,  Qh, dw3h, db3, Ph, 500, 512, 512, 512);                                   // dh3h
  k_hgemm_f32t<<<dim3(16, MT), b256, 0, stream>>>(Ph, xwh, xb, out_xbar, N, 2000, 512, 512); // x_bar
  #undef HGEMM
}

// Round 7
// 1628.923 us; speedup vs baseline: 1.4875x; 1.0270x over previous
//
#include <hip/hip_runtime.h>
#include <cstdint>

typedef _Float16 half8 __attribute__((ext_vector_type(8)));
typedef _Float16 h2f __attribute__((ext_vector_type(2)));
typedef float f32x4 __attribute__((ext_vector_type(4)));

__device__ __forceinline__ float leakyf(float v){ return v > 0.f ? v : 0.01f*v; }
__device__ __forceinline__ float actf(float v, int act){
  if (act == 1) return fmaxf(v, 0.f);
  if (act == 2) return leakyf(v);
  return v;
}
__device__ __forceinline__ unsigned pkh(float a, float b){
  h2f p; p[0]=(_Float16)a; p[1]=(_Float16)b; return __builtin_bit_cast(unsigned, p);
}
__device__ __forceinline__ h2f uph(unsigned u){ return __builtin_bit_cast(h2f, u); }

__device__ __forceinline__ void gl_lds16(const void* g, void* l){
  __builtin_amdgcn_global_load_lds((const __attribute__((address_space(1))) void*)g,
                                   (__attribute__((address_space(3))) void*)l, 16, 0, 0);
}

// bijective XCD-chunked swizzle (m204): consecutive blocks on one XCD share A row-tile
__device__ __forceinline__ void xcd_swz(int& bx, int& by){
  int nx = gridDim.x;
  int nwg = nx * gridDim.y;
  int lid = blockIdx.y*nx + blockIdx.x;
  int q = nwg >> 3, r = nwg & 7;
  int xcd = lid & 7, idx = lid >> 3;
  int w = (xcd < r ? xcd*(q+1) : r*(q+1) + (xcd-r)*q) + idx;
  bx = w % nx; by = w / nx;
}

// ---------------- graph build ----------------
__global__ void k_init_deg(int* deg_out, int* deg_in, int n){
  int i = blockIdx.x*blockDim.x + threadIdx.x;
  if (i < n){ deg_out[i] = 1; deg_in[i] = 1; }
}
__global__ void k_count(const int* __restrict__ src, const int* __restrict__ dst,
                        int* deg_out, int* deg_in, int e){
  int i = blockIdx.x*blockDim.x + threadIdx.x;
  if (i < e){ atomicAdd(&deg_out[src[i]], 1); atomicAdd(&deg_in[dst[i]], 1); }
}
__global__ void k_scan(const int* __restrict__ deg, int* rp, int n){
  __shared__ int sums[1024];
  int t = threadIdx.x;
  int per = (n + 1023)/1024;
  int base = t*per;
  int s = 0;
  for (int i = 0; i < per; ++i){ int j = base+i; if (j < n) s += deg[j]; }
  sums[t] = s; __syncthreads();
  for (int off = 1; off < 1024; off <<= 1){
    int v = 0;
    if (t >= off) v = sums[t-off];
    __syncthreads();
    if (t >= off) sums[t] += v;
    __syncthreads();
  }
  int run = (t == 0) ? 0 : sums[t-1];
  for (int i = 0; i < per; ++i){ int j = base+i; if (j < n){ rp[j] = run; run += deg[j]; } }
  if (t == 1023) rp[n] = sums[1023];
}
__global__ void k_zero_i(int* p, int n){ int i=blockIdx.x*blockDim.x+threadIdx.x; if(i<n) p[i]=0; }
__global__ void k_zero_f(float* p, int n){ int i=blockIdx.x*blockDim.x+threadIdx.x; if(i<n) p[i]=0.f; }
__global__ void k_fill(const int* __restrict__ src, const int* __restrict__ dst,
                       const int* __restrict__ rp, int* cursor, int* ci, int e, int n){
  int i = blockIdx.x*blockDim.x + threadIdx.x;
  if (i >= e + n) return;
  int s, d;
  if (i < e){ s = src[i]; d = dst[i]; } else { s = d = i - e; }
  int pos = atomicAdd(&cursor[d], 1);
  ci[rp[d] + pos] = s;
}
__global__ void k_norms(const int* deg_out, const int* deg_in, float* nsrc, float* ndst, int n){
  int i = blockIdx.x*blockDim.x + threadIdx.x;
  if (i < n){ nsrc[i] = rsqrtf((float)deg_out[i]); ndst[i] = rsqrtf((float)deg_in[i]); }
}

// ---------------- conversions ----------------
__global__ void k_conv_a(const float* __restrict__ in, _Float16* __restrict__ out,
                         int M, int K, int Mp, int Kp){
  long idx = (long)blockIdx.x*blockDim.x + threadIdx.x;
  long total = (long)Mp*(Kp/8);
  if (idx >= total) return;
  int kp8 = Kp/8;
  int m = (int)(idx / kp8);
  int k8 = (int)(idx % kp8) * 8;
  half8 o;
  #pragma unroll
  for (int j=0;j<8;++j){
    int k = k8+j;
    o[j] = (_Float16)((m<M && k<K) ? in[(size_t)m*K + k] : 0.f);
  }
  *(half8*)&out[(size_t)m*Kp + k8] = o;
}
__global__ void k_conv_bt(const float* __restrict__ in, _Float16* __restrict__ out,
                          int K, int N, int Np, int Kp){
  __shared__ float t[32][33];
  int kb = blockIdx.x*32, nb = blockIdx.y*32;
  int tx = threadIdx.x & 31, ty = threadIdx.x >> 5;
  for (int r=ty; r<32; r+=8){
    int k = kb+r, n = nb+tx;
    t[r][tx] = (k<K && n<N) ? in[(size_t)k*N+n] : 0.f;
  }
  __syncthreads();
  for (int r=ty; r<32; r+=8){
    int n = nb+r, k = kb+tx;
    if (n<Np && k<Kp) out[(size_t)n*Kp+k] = (_Float16)t[tx][r];
  }
}

// build Wc [128 x 3136] fp16: packed mlw + block-diag g5 over padded segment layout
__global__ void k_build_wc(const float* __restrict__ mlw, const float* __restrict__ g5,
                           _Float16* __restrict__ wc){
  int idx = blockIdx.x*blockDim.x + threadIdx.x;
  if (idx >= 128*3136) return;
  int c = idx / 3136, k = idx - (idx/3136)*3136;
  int seg = -1, real_k = 0;
  if (k < 512){ if (k < 500){ seg=0; real_k=k; } }
  else if (k < 1024){ int kk=k-512; if (kk<500){ seg=1; real_k=500+kk; } }
  else if (k < 3072){ int kk=k-1024; if (kk<2000){ seg=2; real_k=1000+kk; } }
  else { int kk=k-3072; if (kk<10){ seg=3; real_k=3000+kk; } else if (kk<20){ seg=4; real_k=3010+kk-10; } }
  float val = 0.f;
  if (seg >= 0){
    if (c < 5) val = mlw[(size_t)real_k*5 + c];
    else if (c < 55){ int t=c-5; if (t/10 == seg) val = g5[(size_t)real_k*10 + (t-(t/10)*10)]; }
  }
  wc[(size_t)c*3136 + k] = (_Float16)val;
}

// ---------------- fp16 MFMA GEMM: Ch = act(A @ B^T + bias), fp16 out ----------------
template<int ACT, bool BIAS>
__global__ __launch_bounds__(256) void k_hgemm(
    const _Float16* __restrict__ A, const _Float16* __restrict__ BT,
    const float* __restrict__ bias, _Float16* __restrict__ Ch,
    int M, int Nvalid, long Np, long Kp, long lda)
{
  __shared__ __align__(16) _Float16 Asm[128*32];
  __shared__ __align__(16) _Float16 Bsm[128*32];
  int bx, by; xcd_swz(bx, by);
  const int m0 = by*128, n0 = bx*128;
  const int tid = threadIdx.x;
  const int l = tid & 63, w = tid >> 6;
  const int wr = w >> 1, wc = w & 1;
  const int srow = tid >> 2, sseg = tid & 3;
  f32x4 acc[4][4] = {};

  for (long k0 = 0; k0 < Kp; k0 += 32){
    #pragma unroll
    for (int i=0;i<2;++i){
      int ar = i*64 + srow;
      gl_lds16(A  + (size_t)(m0+ar)*lda + k0 + sseg*8, (char*)Asm + i*4096 + (size_t)tid*16);
      gl_lds16(BT + (size_t)(n0+ar)*Kp + k0 + sseg*8, (char*)Bsm + i*4096 + (size_t)tid*16);
    }
    __syncthreads();
    half8 af[4], bf[4];
    #pragma unroll
    for (int mi=0;mi<4;++mi)
      af[mi] = *(const half8*)&Asm[(size_t)(wr*64 + mi*16 + (l&15))*32 + (l>>4)*8];
    #pragma unroll
    for (int nj=0;nj<4;++nj)
      bf[nj] = *(const half8*)&Bsm[(size_t)(wc*64 + nj*16 + (l&15))*32 + (l>>4)*8];
    #pragma unroll
    for (int mi=0;mi<4;++mi)
      #pragma unroll
      for (int nj=0;nj<4;++nj)
        acc[mi][nj] = __builtin_amdgcn_mfma_f32_16x16x32_f16(af[mi], bf[nj], acc[mi][nj], 0,0,0);
    __syncthreads();
  }

  const int cr = (l>>4)*4, cc = l&15;
  #pragma unroll
  for (int mi=0;mi<4;++mi){
    #pragma unroll
    for (int nj=0;nj<4;++nj){
      int cbase = n0 + wc*64 + nj*16 + cc;
      bool cvalid = cbase < Nvalid;
      #pragma unroll
      for (int q=0;q<4;++q){
        int r = m0 + wr*64 + mi*16 + cr + q;
        float v = acc[mi][nj][q];
        if (BIAS && cvalid) v += bias[cbase];
        if (ACT==1) v = fmaxf(v,0.f); else if (ACT==2) v = leakyf(v);
        if (!cvalid) v = 0.f;
        Ch[(size_t)r*Np + cbase] = (_Float16)(r < M ? v : 0.f);
      }
    }
  }
}

// ---------------- dual GEMM: cols 0-511 = relu(x@ew1+eb1), cols 512-1023 = x@g1 ----------------
__global__ __launch_bounds__(256) void k_hgemm_dual(
    const _Float16* __restrict__ A, const _Float16* __restrict__ BT,
    const float* __restrict__ eb1, _Float16* __restrict__ Ch, int M)
{
  const long Kp = 2048;
  __shared__ __align__(16) _Float16 Asm[128*32];
  __shared__ __align__(16) _Float16 Bsm[128*32];
  int bx, by; xcd_swz(bx, by);
  const int m0 = by*128, n0 = bx*128;
  const int tid = threadIdx.x;
  const int l = tid & 63, w = tid >> 6;
  const int wr = w >> 1, wc = w & 1;
  const int srow = tid >> 2, sseg = tid & 3;
  f32x4 acc[4][4] = {};

  for (long k0 = 0; k0 < Kp; k0 += 32){
    #pragma unroll
    for (int i=0;i<2;++i){
      int ar = i*64 + srow;
      gl_lds16(A  + (size_t)(m0+ar)*Kp + k0 + sseg*8, (char*)Asm + i*4096 + (size_t)tid*16);
      gl_lds16(BT + (size_t)(n0+ar)*Kp + k0 + sseg*8, (char*)Bsm + i*4096 + (size_t)tid*16);
    }
    __syncthreads();
    half8 af[4], bf[4];
    #pragma unroll
    for (int mi=0;mi<4;++mi)
      af[mi] = *(const half8*)&Asm[(size_t)(wr*64 + mi*16 + (l&15))*32 + (l>>4)*8];
    #pragma unroll
    for (int nj=0;nj<4;++nj)
      bf[nj] = *(const half8*)&Bsm[(size_t)(wc*64 + nj*16 + (l&15))*32 + (l>>4)*8];
    #pragma unroll
    for (int mi=0;mi<4;++mi)
      #pragma unroll
      for (int nj=0;nj<4;++nj)
        acc[mi][nj] = __builtin_amdgcn_mfma_f32_16x16x32_f16(af[mi], bf[nj], acc[mi][nj], 0,0,0);
    __syncthreads();
  }

  const int cr = (l>>4)*4, cc = l&15;
  #pragma unroll
  for (int mi=0;mi<4;++mi){
    #pragma unroll
    for (int nj=0;nj<4;++nj){
      int cbase = n0 + wc*64 + nj*16 + cc;
      bool hi = cbase >= 512;
      int cl = hi ? cbase - 512 : cbase;
      bool cvalid = cl < 500;
      #pragma unroll
      for (int q=0;q<4;++q){
        int r = m0 + wr*64 + mi*16 + cr + q;
        float v = acc[mi][nj][q];
        if (!hi && cvalid){ v += eb1[cl]; v = fmaxf(v, 0.f); }
        if (!cvalid) v = 0.f;
        Ch[(size_t)r*1024 + cbase] = (_Float16)(r < M ? v : 0.f);
      }
    }
  }
}

// ---------------- f32-out GEMM with LDS-transposed coalesced epilogue (x_bar) ----------------
__global__ __launch_bounds__(256) void k_hgemm_f32t(
    const _Float16* __restrict__ A, const _Float16* __restrict__ BT,
    const float* __restrict__ bias, float* __restrict__ C,
    int M, int Nvalid, long Kp, long lda)
{
  __shared__ __align__(16) _Float16 Asm[128*32];
  __shared__ __align__(16) _Float16 Bsm[128*32];
  __shared__ __align__(16) float scr[16*128];
  int bx, by; xcd_swz(bx, by);
  const int m0 = by*128, n0 = bx*128;
  const int tid = threadIdx.x;
  const int l = tid & 63, w = tid >> 6;
  const int wr = w >> 1, wc = w & 1;
  const int srow = tid >> 2, sseg = tid & 3;
  f32x4 acc[4][4] = {};

  for (long k0 = 0; k0 < Kp; k0 += 32){
    #pragma unroll
    for (int i=0;i<2;++i){
      int ar = i*64 + srow;
      gl_lds16(A  + (size_t)(m0+ar)*lda + k0 + sseg*8, (char*)Asm + i*4096 + (size_t)tid*16);
      gl_lds16(BT + (size_t)(n0+ar)*Kp + k0 + sseg*8, (char*)Bsm + i*4096 + (size_t)tid*16);
    }
    __syncthreads();
    half8 af[4], bf[4];
    #pragma unroll
    for (int mi=0;mi<4;++mi)
      af[mi] = *(const half8*)&Asm[(size_t)(wr*64 + mi*16 + (l&15))*32 + (l>>4)*8];
    #pragma unroll
    for (int nj=0;nj<4;++nj)
      bf[nj] = *(const half8*)&Bsm[(size_t)(wc*64 + nj*16 + (l&15))*32 + (l>>4)*8];
    #pragma unroll
    for (int mi=0;mi<4;++mi)
      #pragma unroll
      for (int nj=0;nj<4;++nj)
        acc[mi][nj] = __builtin_amdgcn_mfma_f32_16x16x32_f16(af[mi], bf[nj], acc[mi][nj], 0,0,0);
    __syncthreads();
  }

  const int cr = (l>>4)*4, cc = l&15;
  for (int p = 0; p < 8; ++p){
    if (wr == (p>>2)){
      int mi = p & 3;
      #pragma unroll
      for (int nj=0;nj<4;++nj){
        int cb = wc*64 + nj*16 + cc;
        float bv = (n0+cb < Nvalid) ? bias[n0+cb] : 0.f;
        #pragma unroll
        for (int q=0;q<4;++q)
          scr[(cr+q)*128 + cb] = acc[mi][nj][q] + bv;
      }
    }
    __syncthreads();
    #pragma unroll
    for (int j=0;j<2;++j){
      int flat = (tid + j*256)*4;
      int rl = flat >> 7, col = flat & 127;
      int r = m0 + p*16 + rl;
      int cb = n0 + col;
      if (r < M && cb < Nvalid)
        *(f32x4*)&C[(size_t)r*Nvalid + cb] = *(const f32x4*)&scr[flat];
    }
    __syncthreads();
  }
}

// ---------------- up5 GEMM: Y[Mp x 64] = segA @ Wc^T (segmented A) ----------------
__global__ __launch_bounds__(256) void k_hgemm_up5(
    const _Float16* __restrict__ z1h, const _Float16* __restrict__ z2h,
    const _Float16* __restrict__ z3h, const _Float16* __restrict__ z4zh,
    const _Float16* __restrict__ Wc, float* __restrict__ Y, int M)
{
  __shared__ __align__(16) _Float16 Asm[128*32];
  __shared__ __align__(16) _Float16 Bsm[128*32];
  int bx, by; xcd_swz(bx, by);
  const int m0 = by*128;
  const int tid = threadIdx.x;
  const int l = tid & 63, w = tid >> 6;
  const int wr = w >> 1, wc = w & 1;
  const int srow = tid >> 2, sseg = tid & 3;
  f32x4 acc[4][4] = {};

  for (int k0 = 0; k0 < 3136; k0 += 32){
    const _Float16* ab; long astr; int kk;
    if (k0 < 512){ ab=z1h; astr=512; kk=k0; }
    else if (k0 < 1024){ ab=z2h; astr=512; kk=k0-512; }
    else if (k0 < 3072){ ab=z3h; astr=2048; kk=k0-1024; }
    else { ab=z4zh; astr=64; kk=k0-3072; }
    #pragma unroll
    for (int i=0;i<2;++i){
      int ar = i*64 + srow;
      gl_lds16(ab + (size_t)(m0+ar)*astr + kk + sseg*8, (char*)Asm + i*4096 + (size_t)tid*16);
      gl_lds16(Wc + (size_t)ar*3136 + k0 + sseg*8, (char*)Bsm + i*4096 + (size_t)tid*16);
    }
    __syncthreads();
    half8 af[4], bf[4];
    #pragma unroll
    for (int mi=0;mi<4;++mi)
      af[mi] = *(const half8*)&Asm[(size_t)(wr*64 + mi*16 + (l&15))*32 + (l>>4)*8];
    #pragma unroll
    for (int nj=0;nj<4;++nj)
      bf[nj] = *(const half8*)&Bsm[(size_t)(wc*64 + nj*16 + (l&15))*32 + (l>>4)*8];
    #pragma unroll
    for (int mi=0;mi<4;++mi)
      #pragma unroll
      for (int nj=0;nj<4;++nj)
        acc[mi][nj] = __builtin_amdgcn_mfma_f32_16x16x32_f16(af[mi], bf[nj], acc[mi][nj], 0,0,0);
    __syncthreads();
  }

  const int cr = (l>>4)*4, cc = l&15;
  #pragma unroll
  for (int mi=0;mi<4;++mi){
    #pragma unroll
    for (int nj=0;nj<4;++nj){
      int cbase = wc*64 + nj*16 + cc;
      if (cbase >= 64) continue;
      #pragma unroll
      for (int q=0;q<4;++q){
        int r = m0 + wr*64 + mi*16 + cr + q;
        if (r < M) Y[(size_t)r*64 + cbase] = acc[mi][nj][q];
      }
    }
  }
}

// epilogue: u = l2(softmax(leaky(logits+mlb))); pre5 = sum_i u_i * P_i
__global__ void k_up5_fin(const float* __restrict__ Y, const float* __restrict__ mlb,
                          float* __restrict__ pre5, int M){
  int row = blockIdx.x*blockDim.x + threadIdx.x;
  if (row >= M) return;
  const float* y = Y + (size_t)row*64;
  float v[5]; float mx = -1e30f;
  #pragma unroll
  for (int c=0;c<5;++c){ float t = leakyf(y[c] + mlb[c]); v[c]=t; mx=fmaxf(mx,t); }
  float ss=0.f;
  #pragma unroll
  for (int c=0;c<5;++c){ v[c]=expf(v[c]-mx); ss += v[c]*v[c]; }
  float inv = rsqrtf(fmaxf(ss,1e-30f));
  #pragma unroll
  for (int c=0;c<5;++c) v[c] *= inv;
  #pragma unroll
  for (int c=0;c<10;++c){
    float s = 0.f;
    #pragma unroll
    for (int i=0;i<5;++i) s += v[i]*y[5 + 10*i + c];
    pre5[(size_t)row*10 + c] = s;
  }
}

// tail: z4zh[row][0:10]=z4, [10:20]=zlat, rest 0
__global__ void k_tail64(const float* __restrict__ z4, const float* __restrict__ zlat,
                         _Float16* __restrict__ z4zh, int M){
  int idx = blockIdx.x*blockDim.x + threadIdx.x;
  if (idx >= M*64) return;
  int row = idx >> 6, j = idx & 63;
  float v = 0.f;
  if (j < 10) v = z4[(size_t)row*10 + j];
  else if (j < 20) v = zlat[(size_t)row*10 + j - 10];
  z4zh[idx] = (_Float16)v;
}

// ---------------- skinny 10-out GEMM, fp16 A, LDS-staged transposed f32 weights ----------------
__global__ __launch_bounds__(256) void k_skinny10_h(
    const _Float16* __restrict__ A, long lda, const float* __restrict__ W, int K,
    const float* __restrict__ bias, float* __restrict__ out, int M, int act)
{
  __shared__ float wl[10*2000];
  int tid = threadIdx.x;
  for (int idx = tid; idx < K*10; idx += 256){
    int k = idx/10, c = idx - k*10;
    wl[c*K + k] = W[idx];
  }
  __syncthreads();
  int wv = tid >> 6, lane = tid & 63;
  int stride = gridDim.x*4;
  for (int row = blockIdx.x*4 + wv; row < M; row += stride){
    const _Float16* a = A + (size_t)row*lda;
    float acc[10];
    #pragma unroll
    for (int c=0;c<10;++c) acc[c]=0.f;
    for (int k0 = lane*2; k0 < K; k0 += 128){
      h2f t2 = *(const h2f*)(a + k0);
      float v0 = (float)t2[0], v1 = (float)t2[1];
      #pragma unroll
      for (int c=0;c<10;++c) acc[c] += v0*wl[c*K + k0] + v1*wl[c*K + k0 + 1];
    }
    #pragma unroll
    for (int c=0;c<10;++c){
      #pragma unroll
      for (int off=32; off; off>>=1) acc[c] += __shfl_down(acc[c], off);
    }
    if (lane == 0){
      #pragma unroll
      for (int c=0;c<10;++c){
        float v = acc[c] + (bias ? bias[c] : 0.f);
        out[(size_t)row*10 + c] = actf(v, act);
      }
    }
  }
}

// ---------------- fused gate3 + mix3@g4 (linearity: pre4 = mz*(z3@g4) + mt*(tra3@g4)) ----------------
__global__ __launch_bounds__(256) void k_fused3(
    const _Float16* __restrict__ tra, const _Float16* __restrict__ zin,
    const float* __restrict__ m3w, const float* __restrict__ b3,
    const float* __restrict__ g4, float* __restrict__ pre4, int M)
{
  const int K = 2000;
  __shared__ unsigned g4l[5*2000];
  __shared__ unsigned mt01[2000];
  __shared__ unsigned mz01[2000];
  int tid = threadIdx.x;
  for (int k = tid; k < K; k += 256){
    mt01[k] = pkh(m3w[2*k],       m3w[2*k+1]);
    mz01[k] = pkh(m3w[2*(K+k)],   m3w[2*(K+k)+1]);
  }
  for (int idx = tid; idx < K*5; idx += 256){
    int jp = idx / K, k = idx - jp*K;
    g4l[idx] = pkh(g4[(size_t)k*10 + 2*jp], g4[(size_t)k*10 + 2*jp + 1]);
  }
  __syncthreads();
  int wv = tid >> 6, lane = tid & 63;
  int stride = gridDim.x*4;
  for (int row = blockIdx.x*4 + wv; row < M; row += stride){
    const _Float16* tr = tra + (size_t)row*2048;
    const _Float16* zr = zin + (size_t)row*2048;
    float a0=0.f, a1=0.f;
    float t4[10], z4a[10];
    #pragma unroll
    for (int c=0;c<10;++c){ t4[c]=0.f; z4a[c]=0.f; }
    for (int k0 = lane*2; k0 < K; k0 += 128){
      h2f t2 = *(const h2f*)(tr + k0);
      h2f z2 = *(const h2f*)(zr + k0);
      #pragma unroll
      for (int j=0;j<2;++j){
        int k = k0 + j;
        float t = (float)t2[j], z = (float)z2[j];
        h2f mt = uph(mt01[k]); h2f mz = uph(mz01[k]);
        a0 += t*(float)mt[0] + z*(float)mz[0];
        a1 += t*(float)mt[1] + z*(float)mz[1];
        #pragma unroll
        for (int jp=0;jp<5;++jp){
          h2f p = uph(g4l[jp*K + k]);
          float p0 = (float)p[0], p1 = (float)p[1];
          t4[2*jp]   += t*p0;  t4[2*jp+1]  += t*p1;
          z4a[2*jp]  += z*p0;  z4a[2*jp+1] += z*p1;
        }
      }
    }
    #pragma unroll
    for (int off=32; off; off>>=1){
      a0 += __shfl_down(a0,off); a1 += __shfl_down(a1,off);
      #pragma unroll
      for (int c=0;c<10;++c){
        t4[c]  += __shfl_down(t4[c], off);
        z4a[c] += __shfl_down(z4a[c], off);
      }
    }
    if (lane == 0){
      float s0 = leakyf(a0 + b3[0]);
      float s1 = leakyf(a1 + b3[1]);
      float mx = fmaxf(s0, s1);
      float e0 = expf(s0-mx), e1 = expf(s1-mx);
      float inv = rsqrtf(fmaxf(e0*e0 + e1*e1, 1e-30f));
      float mzc = e0*inv, mtc = e1*inv;
      #pragma unroll
      for (int c=0;c<10;++c)
        pre4[(size_t)row*10 + c] = mzc*z4a[c] + mtc*t4[c];
    }
  }
}

// ---------------- fused gate+mix, fp16 in/out ----------------
__global__ void k_gate_mix_hh(const _Float16* __restrict__ tra, long Wpa,
                              const _Float16* __restrict__ zin, long Wpz,
                              const float* __restrict__ w, const float* __restrict__ b,
                              _Float16* __restrict__ mix, int W, long Wpo)
{
  int row = blockIdx.x;
  int tid = threadIdx.x;
  const _Float16* tr = tra + (size_t)row*Wpa;
  const _Float16* zr = zin + (size_t)row*Wpz;
  int c = tid*2;
  h2f t2 = *(const h2f*)(tr + c);
  h2f z2 = *(const h2f*)(zr + c);
  float a0=0.f, a1=0.f;
  #pragma unroll
  for (int j=0;j<2;++j){
    int k = c + j;
    if (k < W){
      float t = (float)t2[j], zv = (float)z2[j];
      a0 += t*w[2*k]   + zv*w[2*(W+k)];
      a1 += t*w[2*k+1] + zv*w[2*(W+k)+1];
    }
  }
  #pragma unroll
  for (int off=32; off; off>>=1){ a0 += __shfl_down(a0,off); a1 += __shfl_down(a1,off); }
  __shared__ float red0[4], red1[4], m01[2];
  int wv = tid>>6, ln = tid&63;
  if (ln==0){ red0[wv]=a0; red1[wv]=a1; }
  __syncthreads();
  if (tid==0){
    float s0 = red0[0]+red0[1]+red0[2]+red0[3] + b[0];
    float s1 = red1[0]+red1[1]+red1[2]+red1[3] + b[1];
    s0 = leakyf(s0); s1 = leakyf(s1);
    float mx = fmaxf(s0,s1);
    float e0 = expf(s0-mx), e1 = expf(s1-mx);
    float inv = rsqrtf(fmaxf(e0*e0+e1*e1, 1e-30f));
    m01[0] = e0*inv; m01[1] = e1*inv;
  }
  __syncthreads();
  float mz = m01[0], mt = m01[1];
  h2f o;
  #pragma unroll
  for (int j=0;j<2;++j){
    int k = c + j;
    o[j] = (_Float16)(k < W ? (mz*(float)z2[j] + mt*(float)t2[j]) : 0.f);
  }
  *(h2f*)(mix + (size_t)row*Wpo + c) = o;
}

// ---------------- SpMM gather, fp16x2 loads; fp16 out ----------------
template<int ACT>
__global__ void k_spmm2(const _Float16* __restrict__ h, long Wpi, const int* __restrict__ rp,
                        const int* __restrict__ ci, const float* __restrict__ nsrc,
                        const float* __restrict__ ndst, _Float16* __restrict__ outh,
                        int W, long Wpo)
{
  int row = blockIdx.x;
  int tid = threadIdx.x;
  int c = tid*2;
  int e0 = rp[row], e1 = rp[row+1];
  float a0=0.f, a1=0.f;
  for (int e=e0; e<e1; ++e){
    int s = ci[e];
    float ns = nsrc[s];
    h2f p = *(const h2f*)(h + (size_t)s*Wpi + c);
    a0 += ns*(float)p[0];
    a1 += ns*(float)p[1];
  }
  float nd = ndst[row];
  a0 = actf(a0*nd, ACT); a1 = actf(a1*nd, ACT);
  h2f o;
  o[0] = (_Float16)(c   < W ? a0 : 0.f);
  o[1] = (_Float16)(c+1 < W ? a1 : 0.f);
  *(h2f*)(outh + (size_t)row*Wpo + c) = o;
}

// ---------------- SpMM gather, width 10 ----------------
template<int ACT>
__global__ void k_spmm10(const float* __restrict__ h, const int* __restrict__ rp,
                         const int* __restrict__ ci, const float* __restrict__ nsrc,
                         const float* __restrict__ ndst, float* __restrict__ out, int n)
{
  int idx = blockIdx.x*blockDim.x + threadIdx.x;
  if (idx >= n*10) return;
  int row = idx/10, c = idx - row*10;
  int e0 = rp[row], e1 = rp[row+1];
  float acc = 0.f;
  for (int e=e0; e<e1; ++e){
    int s = ci[e];
    acc += nsrc[s]*h[(size_t)s*10 + c];
  }
  out[idx] = actf(acc*ndst[row], ACT);
}

// ---------------- decoder layer 1: weights in registers ----------------
__global__ __launch_bounds__(512) void k_broad_reg(
    const float* __restrict__ Z, const float* __restrict__ W, const float* __restrict__ bias,
    _Float16* __restrict__ out, int M, int Mp, int Cc, int Cp)
{
  int tid = threadIdx.x;
  float wr[4][10], bv[4];
  #pragma unroll
  for (int j=0;j<4;++j){
    int c = tid + j*512;
    bool v = c < Cc;
    bv[j] = v ? bias[c] : 0.f;
    #pragma unroll
    for (int q=0;q<10;++q) wr[j][q] = v ? W[(size_t)q*Cc + c] : 0.f;
  }
  for (int row = blockIdx.x; row < Mp; row += gridDim.x){
    float zr[10];
    bool rv = row < M;
    #pragma unroll
    for (int q=0;q<10;++q) zr[q] = rv ? Z[(size_t)row*10 + q] : 0.f;
    #pragma unroll
    for (int j=0;j<4;++j){
      int c = tid + j*512;
      float v = bv[j];
      #pragma unroll
      for (int q=0;q<10;++q) v += zr[q]*wr[j][q];
      v = fmaxf(v, 0.f);
      out[(size_t)row*Cp + c] = (_Float16)((rv && c < Cc) ? v : 0.f);
    }
  }
}

__global__ void k_softmax10(const float* __restrict__ h, float* __restrict__ out, int M){
  int row = blockIdx.x*blockDim.x + threadIdx.x;
  if (row >= M) return;
  float v[10]; float mx=-1e30f;
  #pragma unroll
  for (int j=0;j<10;++j){ v[j]=h[(size_t)row*10+j]; mx=fmaxf(mx,v[j]); }
  float s=0.f;
  #pragma unroll
  for (int j=0;j<10;++j){ v[j]=expf(v[j]-mx); s+=v[j]; }
  float inv=1.f/s;
  #pragma unroll
  for (int j=0;j<10;++j) out[(size_t)row*10+j]=v[j]*inv;
}

__global__ void k_q(const float* __restrict__ z, const float* __restrict__ cluster,
                    float* __restrict__ qout, float* __restrict__ colsum, int M)
{
  __shared__ float part[10];
  if (threadIdx.x < 10) part[threadIdx.x] = 0.f;
  __syncthreads();
  int row = blockIdx.x*blockDim.x + threadIdx.x;
  if (row < M){
    float zr[10];
    #pragma unroll
    for (int j=0;j<10;++j) zr[j] = z[(size_t)row*10+j];
    float qv[10]; float s=0.f;
    #pragma unroll
    for (int k=0;k<10;++k){
      float d2=0.f;
      #pragma unroll
      for (int j=0;j<10;++j){ float t = zr[j]-cluster[k*10+j]; d2 += t*t; }
      float qq = 1.f/(1.f+d2);
      qv[k]=qq; s+=qq;
    }
    float inv = 1.f/s;
    #pragma unroll
    for (int k=0;k<10;++k){
      float val = qv[k]*inv;
      qout[(size_t)row*10+k] = val;
      atomicAdd(&part[k], val);
    }
  }
  __syncthreads();
  if (threadIdx.x < 10) atomicAdd(&colsum[threadIdx.x], part[threadIdx.x]);
}

__global__ void k_p(const float* __restrict__ q, const float* __restrict__ colsum,
                    float* __restrict__ pout, int M){
  int row = blockIdx.x*blockDim.x + threadIdx.x;
  if (row >= M) return;
  float w[10]; float s=0.f;
  #pragma unroll
  for (int k=0;k<10;++k){ float qq=q[(size_t)row*10+k]; float ww=qq*qq/colsum[k]; w[k]=ww; s+=ww; }
  float inv=1.f/s;
  #pragma unroll
  for (int k=0;k<10;++k) pout[(size_t)row*10+k]=w[k]*inv;
}

extern "C" void kernel_launch(void* const* d_in, const int* in_sizes, int n_in,
                              void* d_out, int out_size, void* d_ws, size_t ws_size,
                              hipStream_t stream)
{
  const float* x   = (const float*)d_in[0];
  const float* ew1 = (const float*)d_in[1];  const float* eb1 = (const float*)d_in[2];
  const float* ew2 = (const float*)d_in[3];  const float* eb2 = (const float*)d_in[4];
  const float* ew3 = (const float*)d_in[5];  const float* eb3 = (const float*)d_in[6];
  const float* zw  = (const float*)d_in[7];  const float* zb  = (const float*)d_in[8];
  const float* dw1 = (const float*)d_in[9];  const float* db1 = (const float*)d_in[10];
  const float* dw2 = (const float*)d_in[11]; const float* db2 = (const float*)d_in[12];
  const float* dw3 = (const float*)d_in[13]; const float* db3 = (const float*)d_in[14];
  const float* xw  = (const float*)d_in[15]; const float* xb  = (const float*)d_in[16];
  const float* g1  = (const float*)d_in[17];
  const float* g2  = (const float*)d_in[18];
  const float* g3  = (const float*)d_in[19];
  const float* g4  = (const float*)d_in[20];
  const float* g5  = (const float*)d_in[21];
  const float* m1w = (const float*)d_in[22]; const float* m1b = (const float*)d_in[23];
  const float* m2w = (const float*)d_in[24]; const float* m2b = (const float*)d_in[25];
  const float* m3w = (const float*)d_in[26]; const float* m3b = (const float*)d_in[27];
  const float* mlw = (const float*)d_in[28]; const float* mlb = (const float*)d_in[29];
  const float* cluster = (const float*)d_in[30];
  const int* src = (const int*)d_in[31];
  const int* dst = (const int*)d_in[32];

  const int NI=2000, H1=500, H2=500, H3=2000;
  const int N = in_sizes[0] / NI;      // 20000
  const int E = in_sizes[31];          // 320000
  const int M_tot = E + N;
  const int Mp = ((N + 127)/128)*128;  // 20096

  float* out = (float*)d_out;
  float* out_xbar = out;
  float* out_q    = out + (size_t)N*NI;
  float* out_pred = out_q + (size_t)N*10;
  float* out_p    = out_pred + (size_t)N*10;

  // ---- workspace carve ----
  char* base = (char*)d_ws;
  size_t off = 0;
  auto AF = [&](size_t e)->float*{ float* r=(float*)(base+off); off += ((e*sizeof(float)+15)&~(size_t)15); return r; };
  auto AI = [&](size_t e)->int*  { int*   r=(int*)  (base+off); off += ((e*sizeof(int)  +15)&~(size_t)15); return r; };
  auto AH = [&](size_t e)->_Float16*{ _Float16* r=(_Float16*)(base+off); off += ((e*sizeof(_Float16)+15)&~(size_t)15); return r; };

  int* deg_out = AI(N); int* deg_in = AI(N);
  int* rp = AI(N+1); int* cursor = AI(N); int* ci = AI(M_tot);
  float* nsrc = AF(N); float* ndst = AF(N); float* colsum = AF(16);
  float* zlat = AF((size_t)N*10);
  float* pre4 = AF((size_t)N*10);
  float* z4   = AF((size_t)N*10);
  float* pre5 = AF((size_t)N*10);
  float* hbuf = AF((size_t)N*10);
  float* Ybuf = AF((size_t)Mp*64);
  // fp16 buffers
  _Float16* xh    = AH((size_t)Mp*2048);   // x_h -> z3_h -> dh1_h
  _Float16* tra3h = AH((size_t)Mp*2048);
  _Float16* dualh = AH((size_t)Mp*1024);   // cols 0-511 tra1h | cols 512-1023 pre1h
  _Float16* tra2h = AH((size_t)Mp*512);
  _Float16* z1h   = AH((size_t)Mp*512);
  _Float16* z2h   = AH((size_t)Mp*512);
  _Float16* Ph    = AH((size_t)Mp*512);    // agg2_h -> agg3_h -> dh3_h
  _Float16* Qh    = AH((size_t)Mp*512);    // mix1_h -> mix2_h -> dh2_h
  _Float16* z4zh  = AH((size_t)Mp*64);
  _Float16* wch   = AH((size_t)128*3136);
  _Float16* ewg1h = AH((size_t)1024*2048); // rows 0-511 ew1^T | rows 512-1023 g1^T
  _Float16* ew1h  = ewg1h;
  _Float16* g1h   = ewg1h + (size_t)512*2048;
  _Float16* ew2h = AH((size_t)512*512);
  _Float16* ew3h = AH((size_t)2048*512);
  _Float16* dw2h = AH((size_t)512*2048);
  _Float16* dw3h = AH((size_t)512*512);
  _Float16* xwh  = AH((size_t)2048*512);
  _Float16* g2h  = AH((size_t)512*512);
  _Float16* g3h  = AH((size_t)2048*512);
  (void)ws_size; (void)out_size; (void)n_in;

  dim3 b256(256);
  // ---- graph build ----
  k_init_deg<<<(N+255)/256, b256, 0, stream>>>(deg_out, deg_in, N);
  k_count<<<(E+255)/256, b256, 0, stream>>>(src, dst, deg_out, deg_in, E);
  k_scan<<<1, 1024, 0, stream>>>(deg_in, rp, N);
  k_zero_i<<<(N+255)/256, b256, 0, stream>>>(cursor, N);
  k_zero_f<<<1, 64, 0, stream>>>(colsum, 16);
  k_fill<<<(M_tot+255)/256, b256, 0, stream>>>(src, dst, rp, cursor, ci, E, N);
  k_norms<<<(N+255)/256, b256, 0, stream>>>(deg_out, deg_in, nsrc, ndst, N);

  // ---- conversions ----
  {
    long tot = (long)Mp*(2048/8);
    k_conv_a<<<(tot+255)/256, b256, 0, stream>>>(x, xh, N, NI, Mp, 2048);
  }
  #define CONVBT(W_, K_, N_, NP_, KP_, OUT_) \
    k_conv_bt<<<dim3((KP_)/32,(NP_)/32), b256, 0, stream>>>((W_), (OUT_), (K_), (N_), (NP_), (KP_))
  CONVBT(ew1, 2000, 500, 512, 2048, ew1h);
  CONVBT(g1,  2000, 500, 512, 2048, g1h);
  CONVBT(ew2, 500, 500, 512, 512, ew2h);
  CONVBT(ew3, 500, 2000, 2048, 512, ew3h);
  CONVBT(dw2, 2000, 500, 512, 2048, dw2h);
  CONVBT(dw3, 500, 500, 512, 512, dw3h);
  CONVBT(xw,  500, 2000, 2048, 512, xwh);
  CONVBT(g2,  500, 500, 512, 512, g2h);
  CONVBT(g3,  500, 2000, 2048, 512, g3h);
  #undef CONVBT
  k_build_wc<<<(128*3136+255)/256, b256, 0, stream>>>(mlw, g5, wch);

  const int MT = Mp/128;   // 157
  #define HGEMM(ACT,BIAS, A_,BT_,BIASP_,CH_, NV_,NP_,KP_,LDA_) \
    k_hgemm<ACT,BIAS><<<dim3((NP_)/128, MT), b256, 0, stream>>>( \
      (A_),(BT_),(BIASP_),(CH_), N, (NV_), (NP_), (KP_), (LDA_))

  // ---- encoder + first GCN layer fused on the x pass ----
  k_hgemm_dual<<<dim3(8, MT), b256, 0, stream>>>(xh, ewg1h, eb1, dualh, N);                // tra1h|pre1h
  HGEMM(1,true,  dualh, ew2h, eb2, tra2h, 500, 512, 512, 1024);                            // tra2h
  HGEMM(1,true,  tra2h, ew3h, eb3, tra3h, 2000, 2048, 512, 512);                           // tra3h
  k_skinny10_h<<<512, b256, 0, stream>>>(tra3h, 2048, zw, 2000, zb, zlat, N, 0);           // zlat

  // ---- GCN branch ----
  k_spmm2<2><<<N, b256, 0, stream>>>(dualh+512, 1024, rp, ci, nsrc, ndst, z1h, H1, 512);   // z1h (leaky)
  k_gate_mix_hh<<<N, b256, 0, stream>>>(dualh, 1024, z1h, 512, m1w, m1b, Qh, H1, 512);     // mix1h
  k_spmm2<0><<<N, b256, 0, stream>>>(Qh, 512, rp, ci, nsrc, ndst, Ph, H1, 512);            // agg2h
  HGEMM(2,false, Ph, g2h, nullptr, z2h, 500, 512, 512, 512);                               // z2h (leaky)
  k_gate_mix_hh<<<N, b256, 0, stream>>>(tra2h, 512, z2h, 512, m2w, m2b, Qh, H2, 512);      // mix2h
  k_spmm2<0><<<N, b256, 0, stream>>>(Qh, 512, rp, ci, nsrc, ndst, Ph, H2, 512);            // agg3h
  HGEMM(2,false, Ph, g3h, nullptr, xh, 2000, 2048, 512, 512);                              // z3h (xh slot)
  k_fused3<<<512, b256, 0, stream>>>(tra3h, xh, m3w, m3b, g4, pre4, N);                    // gate3 + mix@g4
  k_spmm10<2><<<(N*10+255)/256, b256, 0, stream>>>(pre4, rp, ci, nsrc, ndst, z4, N);       // z4
  k_tail64<<<(N*64+255)/256, b256, 0, stream>>>(z4, zlat, z4zh, N);
  k_hgemm_up5<<<dim3(1, MT), b256, 0, stream>>>(z1h, z2h, xh, z4zh, wch, Ybuf, N);
  k_up5_fin<<<(N+255)/256, b256, 0, stream>>>(Ybuf, mlb, pre5, N);
  k_spmm10<0><<<(N*10+255)/256, b256, 0, stream>>>(pre5, rp, ci, nsrc, ndst, hbuf, N);
  k_softmax10<<<(N+255)/256, b256, 0, stream>>>(hbuf, out_pred, N);
  // ---- clustering head ----
  k_q<<<(N+255)/256, b256, 0, stream>>>(zlat, cluster, out_q, colsum, N);
  k_p<<<(N+255)/256, b256, 0, stream>>>(out_q, colsum, out_p, N);

  // ---- decoder (xh/z3h dead after up5 GEMM) ----
  k_broad_reg<<<512, 512, 0, stream>>>(zlat, dw1, db1, xh, N, Mp, H3, 2048);               // dh1h
  HGEMM(1,true,  xh, dw2h, db2, Qh, 500, 512, 2048, 2048);                                 // dh2h
  HGEMM(1,true,  Qh, dw3h, db3, Ph, 500, 512, 512, 512);                                   // dh3h
  k_hgemm_f32t<<<dim3(16, MT), b256, 0, stream>>>(Ph, xwh, xb, out_xbar, N, 2000, 512, 512); // x_bar
  #undef HGEMM
}